// Round 3
// baseline (3953.871 us; speedup 1.0000x reference)
//
#include <hip/hip_runtime.h>
#include <hip/hip_cooperative_groups.h>
#include <math.h>

namespace cg = cooperative_groups;

#define N_   1024
#define K_   8
#define OTL  3
#define SKL  3
#define GWBL 2
#define INVB 10.0f      /* 1/PROX_BETA */
#define EPSV 1e-16f
#define NN   ((size_t)N_ * N_)
#define COOPB 512       /* cooperative grid blocks */

typedef __attribute__((ext_vector_type(8))) short short8;
typedef __attribute__((ext_vector_type(4))) float f32x4;
typedef unsigned short bfu;

__device__ __forceinline__ float b2f(bfu u) {
    unsigned x = ((unsigned)u) << 16;
    return __builtin_bit_cast(float, x);
}
__device__ __forceinline__ bfu f2b(float f) {
    unsigned u = __builtin_bit_cast(unsigned, f);
    unsigned r = u + 0x7fffu + ((u >> 16) & 1u);   // RNE (finite values only)
    return (bfu)(r >> 16);
}

/* ============ bf16 MFMA GEMM: C[m][n] = sum_k A[m][k]*B[n][k] ============
   128x128 tile, 256 thr = 4 waves (2x2), 64x64/wave, mfma 16x16x32.
   EPI 0: store C bf16 | EPI 1: store C fp32 * wts[z] | EPI 2: prox in-place */
template<int EPI>
__global__ __launch_bounds__(256, 2)
void bgemm_k(const bfu* __restrict__ A, const bfu* __restrict__ B,
             void* __restrict__ Cp, size_t sA, size_t sB, size_t sC,
             const float* __restrict__ rv, const float* __restrict__ cv,
             const float* __restrict__ wts) {
    __shared__ bfu As[128 * 32];
    __shared__ bfu Bs[128 * 32];

    const int z  = blockIdx.z;
    const int bm = blockIdx.x * 128, bn = blockIdx.y * 128;
    const int tid = threadIdx.x;
    const int lane = tid & 63, wv = tid >> 6;
    const int wr = wv >> 1, wc = wv & 1;

    const bfu* Az = A + (size_t)z * sA;
    const bfu* Bz = B + (size_t)z * sB;

    const int sr = tid >> 2;          // staging row (0..63 per half)
    const int sk = (tid & 3) * 8;     // staging k-offset (elems)
    const int fr = lane & 15;
    const int ks = (lane >> 4) * 8;

    f32x4 acc[4][4];
    #pragma unroll
    for (int i = 0; i < 4; i++)
        #pragma unroll
        for (int j = 0; j < 4; j++) acc[i][j] = (f32x4)0.f;

    for (int k0 = 0; k0 < N_; k0 += 32) {
        __syncthreads();
        #pragma unroll
        for (int h = 0; h < 2; ++h) {
            const int row = sr + h * 64;
            const bfu* ga = Az + (size_t)(bm + row) * N_ + k0 + sk;
            const bfu* gb = Bz + (size_t)(bn + row) * N_ + k0 + sk;
            __builtin_amdgcn_global_load_lds(
                (const __attribute__((address_space(1))) unsigned int*)ga,
                (__attribute__((address_space(3))) unsigned int*)&As[row * 32 + sk],
                16, 0, 0);
            __builtin_amdgcn_global_load_lds(
                (const __attribute__((address_space(1))) unsigned int*)gb,
                (__attribute__((address_space(3))) unsigned int*)&Bs[row * 32 + sk],
                16, 0, 0);
        }
        __syncthreads();

        short8 af[4], bf[4];
        #pragma unroll
        for (int mi = 0; mi < 4; ++mi)
            af[mi] = *(const short8*)&As[(wr * 64 + mi * 16 + fr) * 32 + ks];
        #pragma unroll
        for (int ni = 0; ni < 4; ++ni)
            bf[ni] = *(const short8*)&Bs[(wc * 64 + ni * 16 + fr) * 32 + ks];
        #pragma unroll
        for (int mi = 0; mi < 4; ++mi)
            #pragma unroll
            for (int ni = 0; ni < 4; ++ni)
                acc[mi][ni] = __builtin_amdgcn_mfma_f32_16x16x32_bf16(
                    af[mi], bf[ni], acc[mi][ni], 0, 0, 0);
    }

    const int r0 = bm + wr * 64, c0 = bn + wc * 64;
    const int rq = (lane >> 4) * 4;   // C/D: col=lane&15, row=(lane>>4)*4+q

    if (EPI == 1) {
        float* Cz = (float*)Cp + (size_t)z * sC;
        const float w = wts[z];
        #pragma unroll
        for (int mi = 0; mi < 4; ++mi)
            #pragma unroll
            for (int ni = 0; ni < 4; ++ni)
                #pragma unroll
                for (int q = 0; q < 4; ++q)
                    Cz[(size_t)(r0 + mi * 16 + rq + q) * N_ + c0 + ni * 16 + fr]
                        = w * acc[mi][ni][q];
    } else if (EPI == 0) {
        bfu* Cz = (bfu*)Cp + (size_t)z * sC;
        #pragma unroll
        for (int mi = 0; mi < 4; ++mi)
            #pragma unroll
            for (int ni = 0; ni < 4; ++ni)
                #pragma unroll
                for (int q = 0; q < 4; ++q)
                    Cz[(size_t)(r0 + mi * 16 + rq + q) * N_ + c0 + ni * 16 + fr]
                        = f2b(acc[mi][ni][q]);
    } else {  // EPI == 2: prox in place on Tt
        bfu* Cz = (bfu*)Cp + (size_t)z * sC;
        const float* rvz = rv + z * N_;
        #pragma unroll
        for (int mi = 0; mi < 4; ++mi)
            #pragma unroll
            for (int ni = 0; ni < 4; ++ni)
                #pragma unroll
                for (int q = 0; q < 4; ++q) {
                    const int row = r0 + mi * 16 + rq + q;
                    const int col = c0 + ni * 16 + fr;
                    const float cost = rvz[col] + cv[row] - 2.f * acc[mi][ni][q];
                    const float t = b2f(Cz[(size_t)row * N_ + col]);
                    Cz[(size_t)row * N_ + col] = f2b(expf(-cost * INVB) * t);
                }
    }
}

/* ---- split-K GEMM: P[s][m][n] = sum_{k in slice s} A[m][k]*B[n][k], fp32 ---- */
__global__ __launch_bounds__(256, 2)
void gemm_splitk_k(const bfu* __restrict__ A, const bfu* __restrict__ B,
                   float* __restrict__ P) {
    __shared__ bfu As[128 * 32];
    __shared__ bfu Bs[128 * 32];
    const int bm = blockIdx.x * 128, bn = blockIdx.y * 128;
    const int kbase = blockIdx.z * 256;
    const int tid = threadIdx.x;
    const int lane = tid & 63, wv = tid >> 6;
    const int wr = wv >> 1, wc = wv & 1;
    const int sr = tid >> 2, sk = (tid & 3) * 8;
    const int fr = lane & 15, ks = (lane >> 4) * 8;

    f32x4 acc[4][4];
    #pragma unroll
    for (int i = 0; i < 4; i++)
        #pragma unroll
        for (int j = 0; j < 4; j++) acc[i][j] = (f32x4)0.f;

    for (int k0 = kbase; k0 < kbase + 256; k0 += 32) {
        __syncthreads();
        #pragma unroll
        for (int h = 0; h < 2; ++h) {
            const int row = sr + h * 64;
            __builtin_amdgcn_global_load_lds(
                (const __attribute__((address_space(1))) unsigned int*)
                    (A + (size_t)(bm + row) * N_ + k0 + sk),
                (__attribute__((address_space(3))) unsigned int*)&As[row * 32 + sk],
                16, 0, 0);
            __builtin_amdgcn_global_load_lds(
                (const __attribute__((address_space(1))) unsigned int*)
                    (B + (size_t)(bn + row) * N_ + k0 + sk),
                (__attribute__((address_space(3))) unsigned int*)&Bs[row * 32 + sk],
                16, 0, 0);
        }
        __syncthreads();
        short8 af[4], bf[4];
        #pragma unroll
        for (int mi = 0; mi < 4; ++mi)
            af[mi] = *(const short8*)&As[(wr * 64 + mi * 16 + fr) * 32 + ks];
        #pragma unroll
        for (int ni = 0; ni < 4; ++ni)
            bf[ni] = *(const short8*)&Bs[(wc * 64 + ni * 16 + fr) * 32 + ks];
        #pragma unroll
        for (int mi = 0; mi < 4; ++mi)
            #pragma unroll
            for (int ni = 0; ni < 4; ++ni)
                acc[mi][ni] = __builtin_amdgcn_mfma_f32_16x16x32_bf16(
                    af[mi], bf[ni], acc[mi][ni], 0, 0, 0);
    }

    float* Pz = P + (size_t)blockIdx.z * NN;
    const int r0 = bm + wv / 2 * 64, c0 = bn + (wv & 1) * 64;
    const int rq = (lane >> 4) * 4;
    #pragma unroll
    for (int mi = 0; mi < 4; ++mi)
        #pragma unroll
        for (int ni = 0; ni < 4; ++ni)
            #pragma unroll
            for (int q = 0; q < 4; ++q)
                Pz[(size_t)(r0 + mi * 16 + rq + q) * N_ + c0 + ni * 16 + fr]
                    = acc[mi][ni][q];
}

/* ---- split-K combines ---- */
// EPI 0: Mo = bf16(sum P) | EPI 2: prox into Tt | EPI 3: distance reduce
template<int EPI>
__global__ void comb_k(const float* __restrict__ P, bfu* __restrict__ Tt,
                       const float* __restrict__ rv, const float* __restrict__ cv,
                       float* __restrict__ dout) {
    float bs = 0.f;
    size_t st = (size_t)gridDim.x * blockDim.x;
    for (size_t i4 = blockIdx.x * (size_t)blockDim.x + threadIdx.x; i4 < NN / 4; i4 += st) {
        size_t idx = i4 * 4;
        float4 s = *(const float4*)(P + idx);
        #pragma unroll
        for (int z = 1; z < 4; ++z) {
            float4 v = *(const float4*)(P + (size_t)z * NN + idx);
            s.x += v.x; s.y += v.y; s.z += v.z; s.w += v.w;
        }
        if (EPI == 0) {
            bfu o[4];
            o[0] = f2b(s.x); o[1] = f2b(s.y); o[2] = f2b(s.z); o[3] = f2b(s.w);
            *(ulong1*)&Tt[idx] = *(ulong1*)o;
        } else {
            const int r = (int)(idx >> 10), c = (int)(idx & (N_ - 1));
            const float cvr = cv[r];
            const float4 rvc = *(const float4*)(rv + c);
            bfu t[4];
            *(ulong1*)t = *(const ulong1*)&Tt[idx];
            if (EPI == 2) {
                t[0] = f2b(expf(-(rvc.x + cvr - 2.f * s.x) * INVB) * b2f(t[0]));
                t[1] = f2b(expf(-(rvc.y + cvr - 2.f * s.y) * INVB) * b2f(t[1]));
                t[2] = f2b(expf(-(rvc.z + cvr - 2.f * s.z) * INVB) * b2f(t[2]));
                t[3] = f2b(expf(-(rvc.w + cvr - 2.f * s.w) * INVB) * b2f(t[3]));
                *(ulong1*)&Tt[idx] = *(ulong1*)t;
            } else {  // EPI 3
                bs += (rvc.x + cvr - 2.f * s.x) * b2f(t[0]);
                bs += (rvc.y + cvr - 2.f * s.y) * b2f(t[1]);
                bs += (rvc.z + cvr - 2.f * s.z) * b2f(t[2]);
                bs += (rvc.w + cvr - 2.f * s.w) * b2f(t[3]);
            }
        }
    }
    if (EPI == 3) {
        #pragma unroll
        for (int off = 32; off; off >>= 1) bs += __shfl_down(bs, off);
        __shared__ float wred[4];
        if ((threadIdx.x & 63) == 0) wred[threadIdx.x >> 6] = bs;
        __syncthreads();
        if (threadIdx.x == 0) atomicAdd(dout, wred[0] + wred[1] + wred[2] + wred[3]);
    }
}

/* ============ fused Sinkhorn (cooperative): 3x{b,a} + tupd ============ */
template<int NB>
__global__ __launch_bounds__(256, 2)
void sink_fused_k(bfu* __restrict__ Tt, const float* __restrict__ ps, int pstr,
                  const float* __restrict__ pb,
                  float* __restrict__ av, float* __restrict__ bv) {
    constexpr int RPB = NB * 1024 / COOPB;   // rows/block (b-phase): 16 or 2
    constexpr int CPB = NB * 1024 / COOPB;   // cols/block (a-phase)
    constexpr int RG  = 256 / CPB;           // row-groups: 16 or 128
    constexpr int RPG = 1024 / RG;           // rows per group: 64 or 8

    cg::grid_group grid = cg::this_grid();
    const int blk = blockIdx.x, tid = threadIdx.x;
    const int wv = tid >> 6, lane = tid & 63;
    __shared__ float red[256];

    for (int it = 0; it < SKL; ++it) {
        // ---- b: bv[z*N+j] = pb[j] / (dot(Tt[z][j][:], a[z]) + eps)
        {
            const float* a0  = (it == 0) ? ps : av;
            const int astr   = (it == 0) ? pstr : N_;
            for (int rl = wv; rl < RPB; rl += 4) {
                const int r = blk * RPB + rl;
                const int z = r >> 10, j = r & (N_ - 1);
                const bfu* Tr = Tt + (size_t)z * NN + (size_t)j * N_;
                const float* az = a0 + z * astr;
                float s = 0.f;
                for (int c = lane * 8; c < N_; c += 512) {
                    bfu t[8];
                    *(short8*)t = *(const short8*)&Tr[c];
                    #pragma unroll
                    for (int q = 0; q < 8; ++q) s += b2f(t[q]) * az[c + q];
                }
                #pragma unroll
                for (int off = 32; off; off >>= 1) s += __shfl_down(s, off);
                if (lane == 0) bv[r] = pb[j] / (s + EPSV);
            }
        }
        grid.sync();
        // ---- a: av[z*N+i] = ps[z*pstr+i] / (sum_j Tt[z][j][i]*bv[z*N+j] + eps)
        {
            const int cl = tid % CPB, rg = tid / CPB;
            const int ci = blk * CPB + cl;
            const int z = ci >> 10, i = ci & (N_ - 1);
            const bfu* Tz = Tt + (size_t)z * NN;
            const float* bz = bv + z * N_;
            float s = 0.f;
            for (int j = rg * RPG; j < rg * RPG + RPG; ++j)
                s += b2f(Tz[(size_t)j * N_ + i]) * bz[j];
            red[rg * CPB + cl] = s;
            __syncthreads();
            #pragma unroll
            for (int half = RG / 2; half > 0; half >>= 1) {
                if (rg < half) red[rg * CPB + cl] += red[(rg + half) * CPB + cl];
                __syncthreads();
            }
            if (rg == 0) av[ci] = ps[z * pstr + i] / (red[cl] + EPSV);
            __syncthreads();
        }
        grid.sync();
    }
    // ---- tupd: Tt[z][j][i] *= av[z*N+i] * bv[z*N+j]
    const size_t total8 = (size_t)NB * NN / 8;
    const size_t nthr = (size_t)COOPB * 256;
    for (size_t i8 = (size_t)blk * 256 + tid; i8 < total8; i8 += nthr) {
        const size_t idx = i8 * 8;
        const int z = (int)(idx >> 20);
        const int j = (int)((idx >> 10) & (N_ - 1));
        const int i0 = (int)(idx & (N_ - 1));
        const float bj = bv[z * N_ + j];
        const float* az = av + z * N_;
        bfu t[8];
        *(short8*)t = *(const short8*)&Tt[idx];
        #pragma unroll
        for (int q = 0; q < 8; ++q) t[q] = f2b(b2f(t[q]) * az[i0 + q] * bj);
        *(short8*)&Tt[idx] = *(short8*)t;
    }
}

/* ============ elementwise / reduction kernels ============ */

__global__ void sig2bf_k(const float* __restrict__ x, bfu* __restrict__ y, size_t n4) {
    size_t i = blockIdx.x * (size_t)blockDim.x + threadIdx.x;
    size_t st = (size_t)gridDim.x * blockDim.x;
    for (; i < n4; i += st) {
        float4 v = ((const float4*)x)[i];
        bfu o[4];
        o[0] = f2b(1.f / (1.f + expf(-v.x)));
        o[1] = f2b(1.f / (1.f + expf(-v.y)));
        o[2] = f2b(1.f / (1.f + expf(-v.z)));
        o[3] = f2b(1.f / (1.f + expf(-v.w)));
        *(ulong1*)&y[i * 4] = *(ulong1*)o;
    }
}

// Gmt = Gbt = bf16(Gm); Gb = Gm  (one pass)
__global__ void prep_gm_k(const float* __restrict__ Gm, bfu* __restrict__ Gmt,
                          bfu* __restrict__ Gbt, float* __restrict__ Gb) {
    size_t i = blockIdx.x * (size_t)blockDim.x + threadIdx.x;
    size_t st = (size_t)gridDim.x * blockDim.x;
    for (; i < NN / 4; i += st) {
        float4 v = ((const float4*)Gm)[i];
        ((float4*)Gb)[i] = v;
        bfu o[4];
        o[0] = f2b(v.x); o[1] = f2b(v.y); o[2] = f2b(v.z); o[3] = f2b(v.w);
        *(ulong1*)&Gmt[i * 4] = *(ulong1*)o;
        *(ulong1*)&Gbt[i * 4] = *(ulong1*)o;
    }
}

// Tt[z][j][i] = ps[z*pstr + i] * pb[j]
__global__ void initTt_k(bfu* __restrict__ Tt, const float* __restrict__ ps, int pstr,
                         const float* __restrict__ pb, int nb) {
    size_t total8 = (size_t)nb * NN / 8;
    size_t st = (size_t)gridDim.x * blockDim.x;
    for (size_t i8 = blockIdx.x * (size_t)blockDim.x + threadIdx.x; i8 < total8; i8 += st) {
        size_t idx = i8 * 8;
        int z = (int)(idx >> 20);
        int j = (int)((idx >> 10) & (N_ - 1));
        int i0 = (int)(idx & (N_ - 1));
        float pbj = pb[j];
        const float* pz = ps + z * pstr;
        bfu o[8];
        #pragma unroll
        for (int t = 0; t < 8; ++t) o[t] = f2b(pz[i0 + t] * pbj);
        *(short8*)&Tt[idx] = *(short8*)o;
    }
}

__global__ void copy_k(float* __restrict__ dst, const float* __restrict__ src, size_t n) {
    size_t i = blockIdx.x * (size_t)blockDim.x + threadIdx.x;
    size_t st = (size_t)gridDim.x * blockDim.x;
    for (; i < n; i += st) dst[i] = src[i];
}

__global__ void zero_k(float* p) {
    if (threadIdx.x == 0 && blockIdx.x == 0) p[0] = 0.f;
}

// y[z*N+r] = sum_c sigmoid(atoms[z][r][c])^2 * probs[z*N+c]
__global__ void sqsig_mv_k(const float* __restrict__ atoms, const float* __restrict__ probs,
                           float* __restrict__ y) {
    int z = blockIdx.y;
    int wv = threadIdx.x >> 6, lane = threadIdx.x & 63;
    int r = blockIdx.x * 4 + wv;
    const float* Ar = atoms + (size_t)z * NN + (size_t)r * N_;
    const float* pz = probs + z * N_;
    float s = 0.f;
    for (int c = lane * 4; c < N_; c += 256) {
        float4 v = *(const float4*)(Ar + c);
        float4 p = *(const float4*)(pz + c);
        float sx = 1.f / (1.f + expf(-v.x)), sy = 1.f / (1.f + expf(-v.y));
        float sz = 1.f / (1.f + expf(-v.z)), sw = 1.f / (1.f + expf(-v.w));
        s += sx * sx * p.x + sy * sy * p.y + sz * sz * p.z + sw * sw * p.w;
    }
    #pragma unroll
    for (int off = 32; off; off >>= 1) s += __shfl_down(s, off);
    if (lane == 0) y[z * N_ + r] = s;
}

// y[r] = sum_c A[r][c]^2 * p[c]
__global__ void sq_mv_k(const float* __restrict__ A, const float* __restrict__ p,
                        float* __restrict__ y) {
    int wv = threadIdx.x >> 6, lane = threadIdx.x & 63;
    int r = blockIdx.x * 4 + wv;
    const float* Ar = A + (size_t)r * N_;
    float s = 0.f;
    for (int c = lane * 4; c < N_; c += 256) {
        float4 v = *(const float4*)(Ar + c);
        float4 pv = *(const float4*)(p + c);
        s += v.x * v.x * pv.x + v.y * v.y * pv.y + v.z * v.z * pv.z + v.w * v.w * pv.w;
    }
    #pragma unroll
    for (int off = 32; off; off >>= 1) s += __shfl_down(s, off);
    if (lane == 0) y[r] = s;
}

// Gb[i][j] = (sum_z part[z][i][j]) / (pm[i]*pm[j]);  Gbt = bf16(Gb)
__global__ void reduce8_k(const float* __restrict__ part, const float* __restrict__ pm,
                          float* __restrict__ Gb, bfu* __restrict__ Gbt) {
    size_t st = (size_t)gridDim.x * blockDim.x;
    for (size_t i4 = blockIdx.x * (size_t)blockDim.x + threadIdx.x; i4 < NN / 4; i4 += st) {
        size_t idx = i4 * 4;
        int i = (int)(idx >> 10), j = (int)(idx & (N_ - 1));
        float pi = pm[i];
        float4 pj = *(const float4*)(pm + j);
        float4 s = *(const float4*)(part + idx);
        #pragma unroll
        for (int z = 1; z < K_; ++z) {
            float4 v = *(const float4*)(part + (size_t)z * NN + idx);
            s.x += v.x; s.y += v.y; s.z += v.z; s.w += v.w;
        }
        s.x /= pi * pj.x; s.y /= pi * pj.y; s.z /= pi * pj.z; s.w /= pi * pj.w;
        *(float4*)(Gb + idx) = s;
        bfu o[4];
        o[0] = f2b(s.x); o[1] = f2b(s.y); o[2] = f2b(s.z); o[3] = f2b(s.w);
        *(ulong1*)&Gbt[idx] = *(ulong1*)o;
    }
}

/* ============ host sequence ============ */

extern "C" void kernel_launch(void* const* d_in, const int* in_sizes, int n_in,
                              void* d_out, int out_size, void* d_ws, size_t ws_size,
                              hipStream_t stream) {
    const float* Gm    = (const float*)d_in[0];
    const float* pm    = (const float*)d_in[1];
    const float* atoms = (const float*)d_in[2];
    const float* probs = (const float*)d_in[3];
    const float* wts   = (const float*)d_in[4];
    float* out = (float*)d_out;                  // [0]=d_fgw, [1..]=G_bary (fp32)

    char* base = (char*)d_ws;
    bfu*   Gkt  = (bfu*)base;                    base += K_ * NN * 2;
    bfu*   Tt   = (bfu*)base;                    base += K_ * NN * 2;
    bfu*   M    = (bfu*)base;                    base += K_ * NN * 2;
    float* part = (float*)base;                  base += K_ * NN * 4;
    float* Gb   = (float*)base;                  base += NN * 4;
    bfu*   Gbt  = (bfu*)base;                    base += NN * 2;
    bfu*   Gmt  = (bfu*)base;                    base += NN * 2;
    float* Gk2ps = (float*)base;                 base += K_ * N_ * 4;
    float* Gm2pm = (float*)base;                 base += N_ * 4;
    float* Gb2pb = (float*)base;                 base += N_ * 4;
    float* avec  = (float*)base;                 base += K_ * N_ * 4;
    float* bvec  = (float*)base;                 base += K_ * N_ * 4;

    const dim3 blk(256);
    const dim3 g8(8, 8, K_);
    const dim3 gsk(8, 8, 4);

    int pstrN = N_, pstr0 = 0;
    bfu* TtP = Tt;
    const float* probsP = probs;
    const float* pmP = pm;
    float* avP = avec;
    float* bvP = bvec;
    void* argsB[] = { &TtP, &probsP, &pstrN, &pmP, &avP, &bvP };
    void* args1[] = { &TtP, &pmP,    &pstr0, &pmP, &avP, &bvP };

    // setup
    sig2bf_k<<<2048, blk, 0, stream>>>(atoms, Gkt, K_ * NN / 4);
    sqsig_mv_k<<<dim3(N_ / 4, K_), blk, 0, stream>>>(atoms, probs, Gk2ps);
    sq_mv_k<<<dim3(N_ / 4, 1), blk, 0, stream>>>(Gm, pm, Gm2pm);
    prep_gm_k<<<1024, blk, 0, stream>>>(Gm, Gmt, Gbt, Gb);

    for (int it = 0; it < GWBL; ++it) {
        sq_mv_k<<<dim3(N_ / 4, 1), blk, 0, stream>>>(Gb, pm, Gb2pb);
        initTt_k<<<2048, blk, 0, stream>>>(Tt, probs, N_, pm, K_);
        for (int ot = 0; ot < OTL; ++ot) {
            // M[i][n] = sum_k Gk[i][k] * Tt[n][k]          (= Gs @ T)
            bgemm_k<0><<<g8, blk, 0, stream>>>(Gkt, Tt, M, NN, NN, NN,
                nullptr, nullptr, nullptr);
            // Tt[j][i] = exp(-(Gk2ps[i]+Gb2pb[j]-2*(Gb M^T)[j][i])*INVB) * Tt[j][i]
            bgemm_k<2><<<g8, blk, 0, stream>>>(Gbt, M, Tt, 0, NN, NN,
                Gk2ps, Gb2pb, nullptr);
            hipLaunchCooperativeKernel((const void*)sink_fused_k<K_>,
                dim3(COOPB), blk, argsB, 0, stream);
        }
        // GTt[j][i'] = sum_k Tt[j][k]*Gk[i'][k]            (= (Gk @ T)^T)
        bgemm_k<0><<<g8, blk, 0, stream>>>(Tt, Gkt, M, NN, NN, NN,
            nullptr, nullptr, nullptr);
        // part[z][i][j] = w_z * sum_n Tt[z][i][n]*GTt[z][j][n]  (= w_z T^T G T)
        bgemm_k<1><<<g8, blk, 0, stream>>>(Tt, M, part, NN, NN, NN,
            nullptr, nullptr, wts);
        reduce8_k<<<1024, blk, 0, stream>>>(part, pm, Gb, Gbt);
    }

    // final fgwd(Gm, pm, Gb, pm) — split-K GEMMs (full-chip occupancy)
    sq_mv_k<<<dim3(N_ / 4, 1), blk, 0, stream>>>(Gb, pm, Gb2pb);
    initTt_k<<<2048, blk, 0, stream>>>(Tt, pm, 0, pm, 1);
    for (int ot = 0; ot < OTL; ++ot) {
        gemm_splitk_k<<<gsk, blk, 0, stream>>>(Gmt, Tt, part);
        comb_k<0><<<512, blk, 0, stream>>>(part, M, nullptr, nullptr, nullptr);
        gemm_splitk_k<<<gsk, blk, 0, stream>>>(Gbt, M, part);
        comb_k<2><<<512, blk, 0, stream>>>(part, Tt, Gm2pm, Gb2pb, nullptr);
        hipLaunchCooperativeKernel((const void*)sink_fused_k<1>,
            dim3(COOPB), blk, args1, 0, stream);
    }
    // d = sum_ij (Gm2pm[i] + Gb2pb[j] - 2*(Gm T Gb^T)[i][j]) * T[i][j]
    gemm_splitk_k<<<gsk, blk, 0, stream>>>(Gmt, Tt, part);
    comb_k<0><<<512, blk, 0, stream>>>(part, M, nullptr, nullptr, nullptr);
    gemm_splitk_k<<<gsk, blk, 0, stream>>>(Gbt, M, part);
    zero_k<<<1, 1, 0, stream>>>(out);
    comb_k<3><<<256, blk, 0, stream>>>(part, Tt, Gm2pm, Gb2pb, out);
    copy_k<<<1024, blk, 0, stream>>>(out + 1, Gb, NN);
}

// Round 4
// 899.274 us; speedup vs baseline: 4.3967x; 4.3967x over previous
//
#include <hip/hip_runtime.h>
#include <math.h>

#define N_   1024
#define K_   8
#define OTL  3
#define SKL  3
#define GWBL 2
#define INVB 10.0f      /* 1/PROX_BETA */
#define EPSV 1e-16f
#define NN   ((size_t)N_ * N_)

typedef __attribute__((ext_vector_type(8))) short short8;
typedef __attribute__((ext_vector_type(4))) float f32x4;
typedef unsigned short bfu;

__device__ __forceinline__ float b2f(bfu u) {
    unsigned x = ((unsigned)u) << 16;
    return __builtin_bit_cast(float, x);
}
__device__ __forceinline__ bfu f2b(float f) {
    unsigned u = __builtin_bit_cast(unsigned, f);
    unsigned r = u + 0x7fffu + ((u >> 16) & 1u);   // RNE (finite values only)
    return (bfu)(r >> 16);
}

/* ============ bf16 MFMA GEMM: C[m][n] = sum_k A[m][k]*B[n][k] ============
   128x128 tile, 256 thr = 4 waves (2x2), 64x64/wave, mfma 16x16x32.
   EPI 0: store C bf16 | EPI 1: store C fp32 * wts[z] | EPI 2: prox in-place */
template<int EPI>
__global__ __launch_bounds__(256, 2)
void bgemm_k(const bfu* __restrict__ A, const bfu* __restrict__ B,
             void* __restrict__ Cp, size_t sA, size_t sB, size_t sC,
             const float* __restrict__ rv, const float* __restrict__ cv,
             const float* __restrict__ wts) {
    __shared__ bfu As[128 * 32];
    __shared__ bfu Bs[128 * 32];

    const int z  = blockIdx.z;
    const int bm = blockIdx.x * 128, bn = blockIdx.y * 128;
    const int tid = threadIdx.x;
    const int lane = tid & 63, wv = tid >> 6;
    const int wr = wv >> 1, wc = wv & 1;

    const bfu* Az = A + (size_t)z * sA;
    const bfu* Bz = B + (size_t)z * sB;

    const int sr = tid >> 2;          // staging row (0..63 per half)
    const int sk = (tid & 3) * 8;     // staging k-offset (elems)
    const int fr = lane & 15;
    const int ks = (lane >> 4) * 8;

    f32x4 acc[4][4];
    #pragma unroll
    for (int i = 0; i < 4; i++)
        #pragma unroll
        for (int j = 0; j < 4; j++) acc[i][j] = (f32x4)0.f;

    for (int k0 = 0; k0 < N_; k0 += 32) {
        __syncthreads();
        #pragma unroll
        for (int h = 0; h < 2; ++h) {
            const int row = sr + h * 64;
            const bfu* ga = Az + (size_t)(bm + row) * N_ + k0 + sk;
            const bfu* gb = Bz + (size_t)(bn + row) * N_ + k0 + sk;
            __builtin_amdgcn_global_load_lds(
                (const __attribute__((address_space(1))) unsigned int*)ga,
                (__attribute__((address_space(3))) unsigned int*)&As[row * 32 + sk],
                16, 0, 0);
            __builtin_amdgcn_global_load_lds(
                (const __attribute__((address_space(1))) unsigned int*)gb,
                (__attribute__((address_space(3))) unsigned int*)&Bs[row * 32 + sk],
                16, 0, 0);
        }
        __syncthreads();

        short8 af[4], bf[4];
        #pragma unroll
        for (int mi = 0; mi < 4; ++mi)
            af[mi] = *(const short8*)&As[(wr * 64 + mi * 16 + fr) * 32 + ks];
        #pragma unroll
        for (int ni = 0; ni < 4; ++ni)
            bf[ni] = *(const short8*)&Bs[(wc * 64 + ni * 16 + fr) * 32 + ks];
        #pragma unroll
        for (int mi = 0; mi < 4; ++mi)
            #pragma unroll
            for (int ni = 0; ni < 4; ++ni)
                acc[mi][ni] = __builtin_amdgcn_mfma_f32_16x16x32_bf16(
                    af[mi], bf[ni], acc[mi][ni], 0, 0, 0);
    }

    const int r0 = bm + wr * 64, c0 = bn + wc * 64;
    const int rq = (lane >> 4) * 4;   // C/D: col=lane&15, row=(lane>>4)*4+q

    if (EPI == 1) {
        float* Cz = (float*)Cp + (size_t)z * sC;
        const float w = wts[z];
        #pragma unroll
        for (int mi = 0; mi < 4; ++mi)
            #pragma unroll
            for (int ni = 0; ni < 4; ++ni)
                #pragma unroll
                for (int q = 0; q < 4; ++q)
                    Cz[(size_t)(r0 + mi * 16 + rq + q) * N_ + c0 + ni * 16 + fr]
                        = w * acc[mi][ni][q];
    } else if (EPI == 0) {
        bfu* Cz = (bfu*)Cp + (size_t)z * sC;
        #pragma unroll
        for (int mi = 0; mi < 4; ++mi)
            #pragma unroll
            for (int ni = 0; ni < 4; ++ni)
                #pragma unroll
                for (int q = 0; q < 4; ++q)
                    Cz[(size_t)(r0 + mi * 16 + rq + q) * N_ + c0 + ni * 16 + fr]
                        = f2b(acc[mi][ni][q]);
    } else {  // EPI == 2: prox in place on Tt
        bfu* Cz = (bfu*)Cp + (size_t)z * sC;
        const float* rvz = rv + z * N_;
        #pragma unroll
        for (int mi = 0; mi < 4; ++mi)
            #pragma unroll
            for (int ni = 0; ni < 4; ++ni)
                #pragma unroll
                for (int q = 0; q < 4; ++q) {
                    const int row = r0 + mi * 16 + rq + q;
                    const int col = c0 + ni * 16 + fr;
                    const float cost = rvz[col] + cv[row] - 2.f * acc[mi][ni][q];
                    const float t = b2f(Cz[(size_t)row * N_ + col]);
                    Cz[(size_t)row * N_ + col] = f2b(expf(-cost * INVB) * t);
                }
    }
}

/* ---- split-K GEMM: P[s][m][n] = sum_{k in slice s} A[m][k]*B[n][k], fp32 ---- */
__global__ __launch_bounds__(256, 2)
void gemm_splitk_k(const bfu* __restrict__ A, const bfu* __restrict__ B,
                   float* __restrict__ P) {
    __shared__ bfu As[128 * 32];
    __shared__ bfu Bs[128 * 32];
    const int bm = blockIdx.x * 128, bn = blockIdx.y * 128;
    const int kbase = blockIdx.z * 256;
    const int tid = threadIdx.x;
    const int lane = tid & 63, wv = tid >> 6;
    const int wr = wv >> 1, wc = wv & 1;
    const int sr = tid >> 2, sk = (tid & 3) * 8;
    const int fr = lane & 15, ks = (lane >> 4) * 8;

    f32x4 acc[4][4];
    #pragma unroll
    for (int i = 0; i < 4; i++)
        #pragma unroll
        for (int j = 0; j < 4; j++) acc[i][j] = (f32x4)0.f;

    for (int k0 = kbase; k0 < kbase + 256; k0 += 32) {
        __syncthreads();
        #pragma unroll
        for (int h = 0; h < 2; ++h) {
            const int row = sr + h * 64;
            __builtin_amdgcn_global_load_lds(
                (const __attribute__((address_space(1))) unsigned int*)
                    (A + (size_t)(bm + row) * N_ + k0 + sk),
                (__attribute__((address_space(3))) unsigned int*)&As[row * 32 + sk],
                16, 0, 0);
            __builtin_amdgcn_global_load_lds(
                (const __attribute__((address_space(1))) unsigned int*)
                    (B + (size_t)(bn + row) * N_ + k0 + sk),
                (__attribute__((address_space(3))) unsigned int*)&Bs[row * 32 + sk],
                16, 0, 0);
        }
        __syncthreads();
        short8 af[4], bf[4];
        #pragma unroll
        for (int mi = 0; mi < 4; ++mi)
            af[mi] = *(const short8*)&As[(wr * 64 + mi * 16 + fr) * 32 + ks];
        #pragma unroll
        for (int ni = 0; ni < 4; ++ni)
            bf[ni] = *(const short8*)&Bs[(wc * 64 + ni * 16 + fr) * 32 + ks];
        #pragma unroll
        for (int mi = 0; mi < 4; ++mi)
            #pragma unroll
            for (int ni = 0; ni < 4; ++ni)
                acc[mi][ni] = __builtin_amdgcn_mfma_f32_16x16x32_bf16(
                    af[mi], bf[ni], acc[mi][ni], 0, 0, 0);
    }

    float* Pz = P + (size_t)blockIdx.z * NN;
    const int r0 = bm + wv / 2 * 64, c0 = bn + (wv & 1) * 64;
    const int rq = (lane >> 4) * 4;
    #pragma unroll
    for (int mi = 0; mi < 4; ++mi)
        #pragma unroll
        for (int ni = 0; ni < 4; ++ni)
            #pragma unroll
            for (int q = 0; q < 4; ++q)
                Pz[(size_t)(r0 + mi * 16 + rq + q) * N_ + c0 + ni * 16 + fr]
                    = acc[mi][ni][q];
}

/* ---- split-K combines: EPI 0: M=bf16(sum P) | 2: prox into Tt | 3: distance ---- */
template<int EPI>
__global__ void comb_k(const float* __restrict__ P, bfu* __restrict__ Tt,
                       const float* __restrict__ rv, const float* __restrict__ cv,
                       float* __restrict__ dout) {
    float bs = 0.f;
    size_t st = (size_t)gridDim.x * blockDim.x;
    for (size_t i4 = blockIdx.x * (size_t)blockDim.x + threadIdx.x; i4 < NN / 4; i4 += st) {
        size_t idx = i4 * 4;
        float4 s = *(const float4*)(P + idx);
        #pragma unroll
        for (int z = 1; z < 4; ++z) {
            float4 v = *(const float4*)(P + (size_t)z * NN + idx);
            s.x += v.x; s.y += v.y; s.z += v.z; s.w += v.w;
        }
        if (EPI == 0) {
            bfu o[4];
            o[0] = f2b(s.x); o[1] = f2b(s.y); o[2] = f2b(s.z); o[3] = f2b(s.w);
            *(ulong1*)&Tt[idx] = *(ulong1*)o;
        } else {
            const int r = (int)(idx >> 10), c = (int)(idx & (N_ - 1));
            const float cvr = cv[r];
            const float4 rvc = *(const float4*)(rv + c);
            bfu t[4];
            *(ulong1*)t = *(const ulong1*)&Tt[idx];
            if (EPI == 2) {
                t[0] = f2b(expf(-(rvc.x + cvr - 2.f * s.x) * INVB) * b2f(t[0]));
                t[1] = f2b(expf(-(rvc.y + cvr - 2.f * s.y) * INVB) * b2f(t[1]));
                t[2] = f2b(expf(-(rvc.z + cvr - 2.f * s.z) * INVB) * b2f(t[2]));
                t[3] = f2b(expf(-(rvc.w + cvr - 2.f * s.w) * INVB) * b2f(t[3]));
                *(ulong1*)&Tt[idx] = *(ulong1*)t;
            } else {  // EPI 3
                bs += (rvc.x + cvr - 2.f * s.x) * b2f(t[0]);
                bs += (rvc.y + cvr - 2.f * s.y) * b2f(t[1]);
                bs += (rvc.z + cvr - 2.f * s.z) * b2f(t[2]);
                bs += (rvc.w + cvr - 2.f * s.w) * b2f(t[3]);
            }
        }
    }
    if (EPI == 3) {
        #pragma unroll
        for (int off = 32; off; off >>= 1) bs += __shfl_down(bs, off);
        __shared__ float wred[4];
        if ((threadIdx.x & 63) == 0) wred[threadIdx.x >> 6] = bs;
        __syncthreads();
        if (threadIdx.x == 0) atomicAdd(dout, wred[0] + wred[1] + wred[2] + wred[3]);
    }
}

/* ============ rank-1 first OT step: prox kernel without GEMMs ============
   Tt[z][j][i] = exp(-(c2[z*zs+i] + d2[j] - 2*u[z*zs+i]*w[j])*INVB)
                 * ps[z*zs+i] * pb[j]                                        */
__global__ void prox1_k(bfu* __restrict__ Tt, const float* __restrict__ c2,
                        const float* __restrict__ u, const float* __restrict__ d2,
                        const float* __restrict__ w, const float* __restrict__ ps,
                        const float* __restrict__ pb, int zs, int nb) {
    size_t total8 = (size_t)nb * NN / 8;
    size_t st = (size_t)gridDim.x * blockDim.x;
    for (size_t i8 = blockIdx.x * (size_t)blockDim.x + threadIdx.x; i8 < total8; i8 += st) {
        size_t idx = i8 * 8;
        int z = (int)(idx >> 20);
        int j = (int)((idx >> 10) & (N_ - 1));
        int i0 = (int)(idx & (N_ - 1));
        const float d2j = d2[j], wj = w[j], pbj = pb[j];
        const float* c2z = c2 + z * zs + i0;
        const float* uz  = u  + z * zs + i0;
        const float* psz = ps + z * zs + i0;
        bfu o[8];
        #pragma unroll
        for (int t = 0; t < 8; ++t) {
            const float cost = c2z[t] + d2j - 2.f * uz[t] * wj;
            o[t] = f2b(expf(-cost * INVB) * psz[t] * pbj);
        }
        *(short8*)&Tt[idx] = *(short8*)o;
    }
}

/* ============ Sinkhorn kernels ============ */

// bv[z*N+j] = pb[j] / (dot(Tt[z][j][:], a0[z*astr..]) + eps) — wave/row, grid (N/4, nb)
__global__ void sinkb_k(const bfu* __restrict__ Tt, const float* __restrict__ a0,
                        int astr, const float* __restrict__ pb, float* __restrict__ bv) {
    int z = blockIdx.y;
    int wv = threadIdx.x >> 6, lane = threadIdx.x & 63;
    int j = blockIdx.x * 4 + wv;
    const bfu* Tr = Tt + (size_t)z * NN + (size_t)j * N_;
    const float* az = a0 + z * astr;
    float s = 0.f;
    for (int c = lane * 8; c < N_; c += 512) {
        bfu t[8];
        *(short8*)t = *(const short8*)&Tr[c];
        #pragma unroll
        for (int q = 0; q < 8; ++q) s += b2f(t[q]) * az[c + q];
    }
    #pragma unroll
    for (int off = 32; off; off >>= 1) s += __shfl_down(s, off);
    if (lane == 0) bv[z * N_ + j] = pb[j] / (s + EPSV);
}

// av[z*N+i] = ps[z*pstr+i] / (sum_j Tt[z][j][i]*bv[z*N+j] + eps)
// grid (N/64, nb), 1024 threads: 64-col stripe x 16 rowgroups of 64 rows
__global__ __launch_bounds__(1024)
void sinka_k(const bfu* __restrict__ Tt, const float* __restrict__ bv,
             const float* __restrict__ ps, int pstr, float* __restrict__ av) {
    int z = blockIdx.y;
    int cl = threadIdx.x & 63, rg = threadIdx.x >> 6;
    int i = blockIdx.x * 64 + cl;
    const bfu* Tz = Tt + (size_t)z * NN;
    const float* bz = bv + z * N_;
    float s = 0.f;
    #pragma unroll 8
    for (int j = rg * 64; j < rg * 64 + 64; ++j)
        s += b2f(Tz[(size_t)j * N_ + i]) * bz[j];
    __shared__ float red[16][64];
    red[rg][cl] = s;
    __syncthreads();
    #pragma unroll
    for (int h = 8; h > 0; h >>= 1) {
        if (rg < h) red[rg][cl] += red[rg + h][cl];
        __syncthreads();
    }
    if (rg == 0) av[z * N_ + i] = ps[z * pstr + i] / (red[0][cl] + EPSV);
}

// Tt[z][j][i] *= av[z*N+i] * bv[z*N+j]
__global__ void tupd_k(bfu* __restrict__ Tt, const float* __restrict__ av,
                       const float* __restrict__ bv, int nb) {
    size_t total8 = (size_t)nb * NN / 8;
    size_t st = (size_t)gridDim.x * blockDim.x;
    for (size_t i8 = blockIdx.x * (size_t)blockDim.x + threadIdx.x; i8 < total8; i8 += st) {
        size_t idx = i8 * 8;
        int z = (int)(idx >> 20);
        int j = (int)((idx >> 10) & (N_ - 1));
        int i0 = (int)(idx & (N_ - 1));
        const float bj = bv[z * N_ + j];
        const float* az = av + z * N_;
        bfu t[8];
        *(short8*)t = *(const short8*)&Tt[idx];
        #pragma unroll
        for (int q = 0; q < 8; ++q) t[q] = f2b(b2f(t[q]) * az[i0 + q] * bj);
        *(short8*)&Tt[idx] = *(short8*)t;
    }
}

/* ============ elementwise / reduction kernels ============ */

__global__ void sig2bf_k(const float* __restrict__ x, bfu* __restrict__ y, size_t n4) {
    size_t i = blockIdx.x * (size_t)blockDim.x + threadIdx.x;
    size_t st = (size_t)gridDim.x * blockDim.x;
    for (; i < n4; i += st) {
        float4 v = ((const float4*)x)[i];
        bfu o[4];
        o[0] = f2b(1.f / (1.f + expf(-v.x)));
        o[1] = f2b(1.f / (1.f + expf(-v.y)));
        o[2] = f2b(1.f / (1.f + expf(-v.z)));
        o[3] = f2b(1.f / (1.f + expf(-v.w)));
        *(ulong1*)&y[i * 4] = *(ulong1*)o;
    }
}

// Gmt = Gbt = bf16(Gm); Gb = Gm  (one pass)
__global__ void prep_gm_k(const float* __restrict__ Gm, bfu* __restrict__ Gmt,
                          bfu* __restrict__ Gbt, float* __restrict__ Gb) {
    size_t i = blockIdx.x * (size_t)blockDim.x + threadIdx.x;
    size_t st = (size_t)gridDim.x * blockDim.x;
    for (; i < NN / 4; i += st) {
        float4 v = ((const float4*)Gm)[i];
        ((float4*)Gb)[i] = v;
        bfu o[4];
        o[0] = f2b(v.x); o[1] = f2b(v.y); o[2] = f2b(v.z); o[3] = f2b(v.w);
        *(ulong1*)&Gmt[i * 4] = *(ulong1*)o;
        *(ulong1*)&Gbt[i * 4] = *(ulong1*)o;
    }
}

__global__ void copy_k(float* __restrict__ dst, const float* __restrict__ src, size_t n) {
    size_t i = blockIdx.x * (size_t)blockDim.x + threadIdx.x;
    size_t st = (size_t)gridDim.x * blockDim.x;
    for (; i < n; i += st) dst[i] = src[i];
}

__global__ void zero_k(float* p) {
    if (threadIdx.x == 0 && blockIdx.x == 0) p[0] = 0.f;
}

// dual-output: y2[z*N+r] = sum_c sig(atoms)^2 * probs;  y1 = sum_c sig(atoms) * probs
__global__ void sqsig_mv_k(const float* __restrict__ atoms, const float* __restrict__ probs,
                           float* __restrict__ y2, float* __restrict__ y1) {
    int z = blockIdx.y;
    int wv = threadIdx.x >> 6, lane = threadIdx.x & 63;
    int r = blockIdx.x * 4 + wv;
    const float* Ar = atoms + (size_t)z * NN + (size_t)r * N_;
    const float* pz = probs + z * N_;
    float s2 = 0.f, s1 = 0.f;
    for (int c = lane * 4; c < N_; c += 256) {
        float4 v = *(const float4*)(Ar + c);
        float4 p = *(const float4*)(pz + c);
        float sx = 1.f / (1.f + expf(-v.x)), sy = 1.f / (1.f + expf(-v.y));
        float sz = 1.f / (1.f + expf(-v.z)), sw = 1.f / (1.f + expf(-v.w));
        s2 += sx * sx * p.x + sy * sy * p.y + sz * sz * p.z + sw * sw * p.w;
        s1 += sx * p.x + sy * p.y + sz * p.z + sw * p.w;
    }
    #pragma unroll
    for (int off = 32; off; off >>= 1) {
        s2 += __shfl_down(s2, off);
        s1 += __shfl_down(s1, off);
    }
    if (lane == 0) { y2[z * N_ + r] = s2; y1[z * N_ + r] = s1; }
}

// dual-output fp32: y2[r] = sum_c A[r][c]^2 p[c];  y1[r] = sum_c A[r][c] p[c]
__global__ void sq_mv_k(const float* __restrict__ A, const float* __restrict__ p,
                        float* __restrict__ y2, float* __restrict__ y1) {
    int wv = threadIdx.x >> 6, lane = threadIdx.x & 63;
    int r = blockIdx.x * 4 + wv;
    const float* Ar = A + (size_t)r * N_;
    float s2 = 0.f, s1 = 0.f;
    for (int c = lane * 4; c < N_; c += 256) {
        float4 v = *(const float4*)(Ar + c);
        float4 pv = *(const float4*)(p + c);
        s2 += v.x * v.x * pv.x + v.y * v.y * pv.y + v.z * v.z * pv.z + v.w * v.w * pv.w;
        s1 += v.x * pv.x + v.y * pv.y + v.z * pv.z + v.w * pv.w;
    }
    #pragma unroll
    for (int off = 32; off; off >>= 1) {
        s2 += __shfl_down(s2, off);
        s1 += __shfl_down(s1, off);
    }
    if (lane == 0) { y2[r] = s2; y1[r] = s1; }
}

// Gb[i][j] = (sum_z part[z][i][j]) / (pm[i]*pm[j]);  Gbt = bf16(Gb)
__global__ void reduce8_k(const float* __restrict__ part, const float* __restrict__ pm,
                          float* __restrict__ Gb, bfu* __restrict__ Gbt) {
    size_t st = (size_t)gridDim.x * blockDim.x;
    for (size_t i4 = blockIdx.x * (size_t)blockDim.x + threadIdx.x; i4 < NN / 4; i4 += st) {
        size_t idx = i4 * 4;
        int i = (int)(idx >> 10), j = (int)(idx & (N_ - 1));
        float pi = pm[i];
        float4 pj = *(const float4*)(pm + j);
        float4 s = *(const float4*)(part + idx);
        #pragma unroll
        for (int z = 1; z < K_; ++z) {
            float4 v = *(const float4*)(part + (size_t)z * NN + idx);
            s.x += v.x; s.y += v.y; s.z += v.z; s.w += v.w;
        }
        s.x /= pi * pj.x; s.y /= pi * pj.y; s.z /= pi * pj.z; s.w /= pi * pj.w;
        *(float4*)(Gb + idx) = s;
        bfu o[4];
        o[0] = f2b(s.x); o[1] = f2b(s.y); o[2] = f2b(s.z); o[3] = f2b(s.w);
        *(ulong1*)&Gbt[idx] = *(ulong1*)o;
    }
}

/* ============ host sequence ============ */

static inline void sink_seq(bfu* Tt, const float* ps, int pstr, const float* pm,
                            float* avec, float* bvec, int nb, hipStream_t stream) {
    const dim3 blk(256);
    const dim3 gb(N_ / 4, nb), ga(N_ / 64, nb);
    sinkb_k<<<gb, blk, 0, stream>>>(Tt, ps, pstr, pm, bvec);
    sinka_k<<<ga, dim3(1024), 0, stream>>>(Tt, bvec, ps, pstr, avec);
    for (int s = 1; s < SKL; ++s) {
        sinkb_k<<<gb, blk, 0, stream>>>(Tt, avec, N_, pm, bvec);
        sinka_k<<<ga, dim3(1024), 0, stream>>>(Tt, bvec, ps, pstr, avec);
    }
    tupd_k<<<2048, blk, 0, stream>>>(Tt, avec, bvec, nb);
}

extern "C" void kernel_launch(void* const* d_in, const int* in_sizes, int n_in,
                              void* d_out, int out_size, void* d_ws, size_t ws_size,
                              hipStream_t stream) {
    const float* Gm    = (const float*)d_in[0];
    const float* pm    = (const float*)d_in[1];
    const float* atoms = (const float*)d_in[2];
    const float* probs = (const float*)d_in[3];
    const float* wts   = (const float*)d_in[4];
    float* out = (float*)d_out;                  // [0]=d_fgw, [1..]=G_bary (fp32)

    char* base = (char*)d_ws;
    bfu*   Gkt  = (bfu*)base;                    base += K_ * NN * 2;
    bfu*   Tt   = (bfu*)base;                    base += K_ * NN * 2;
    bfu*   M    = (bfu*)base;                    base += K_ * NN * 2;
    float* part = (float*)base;                  base += K_ * NN * 4;
    float* Gb   = (float*)base;                  base += NN * 4;
    bfu*   Gbt  = (bfu*)base;                    base += NN * 2;
    bfu*   Gmt  = (bfu*)base;                    base += NN * 2;
    float* Gk2ps = (float*)base;                 base += K_ * N_ * 4;
    float* Gku   = (float*)base;                 base += K_ * N_ * 4;
    float* Gm2pm = (float*)base;                 base += N_ * 4;
    float* Gmu   = (float*)base;                 base += N_ * 4;
    float* Gb2pb = (float*)base;                 base += N_ * 4;
    float* Gbw   = (float*)base;                 base += N_ * 4;
    float* avec  = (float*)base;                 base += K_ * N_ * 4;
    float* bvec  = (float*)base;                 base += K_ * N_ * 4;

    const dim3 blk(256);
    const dim3 g8(8, 8, K_);
    const dim3 gsk(8, 8, 4);

    // setup
    sig2bf_k<<<2048, blk, 0, stream>>>(atoms, Gkt, K_ * NN / 4);
    sqsig_mv_k<<<dim3(N_ / 4, K_), blk, 0, stream>>>(atoms, probs, Gk2ps, Gku);
    sq_mv_k<<<dim3(N_ / 4, 1), blk, 0, stream>>>(Gm, pm, Gm2pm, Gmu);
    prep_gm_k<<<1024, blk, 0, stream>>>(Gm, Gmt, Gbt, Gb);

    for (int it = 0; it < GWBL; ++it) {
        sq_mv_k<<<dim3(N_ / 4, 1), blk, 0, stream>>>(Gb, pm, Gb2pb, Gbw);
        // ---- OT step 0: rank-1 analytic prox (T0 = ps pb^T), no GEMMs ----
        prox1_k<<<2048, blk, 0, stream>>>(Tt, Gk2ps, Gku, Gb2pb, Gbw,
                                          probs, pm, N_, K_);
        sink_seq(Tt, probs, N_, pm, avec, bvec, K_, stream);
        for (int ot = 1; ot < OTL; ++ot) {
            // M[i][n] = sum_k Gk[i][k] * Tt[n][k]          (= Gs @ T)
            bgemm_k<0><<<g8, blk, 0, stream>>>(Gkt, Tt, M, NN, NN, NN,
                nullptr, nullptr, nullptr);
            // Tt[j][i] = exp(-(Gk2ps[i]+Gb2pb[j]-2*(Gb M^T)[j][i])*INVB) * Tt[j][i]
            bgemm_k<2><<<g8, blk, 0, stream>>>(Gbt, M, Tt, 0, NN, NN,
                Gk2ps, Gb2pb, nullptr);
            sink_seq(Tt, probs, N_, pm, avec, bvec, K_, stream);
        }
        // GTt[j][i'] = sum_k Tt[j][k]*Gk[i'][k]            (= (Gk @ T)^T)
        bgemm_k<0><<<g8, blk, 0, stream>>>(Tt, Gkt, M, NN, NN, NN,
            nullptr, nullptr, nullptr);
        // part[z][i][j] = w_z * sum_n Tt[z][i][n]*GTt[z][j][n]  (= w_z T^T G T)
        bgemm_k<1><<<g8, blk, 0, stream>>>(Tt, M, part, NN, NN, NN,
            nullptr, nullptr, wts);
        reduce8_k<<<1024, blk, 0, stream>>>(part, pm, Gb, Gbt);
    }

    // ---- final fgwd(Gm, pm, Gb, pm) ----
    sq_mv_k<<<dim3(N_ / 4, 1), blk, 0, stream>>>(Gb, pm, Gb2pb, Gbw);
    // OT step 0: rank-1 analytic prox (T0 = pm pm^T)
    prox1_k<<<2048, blk, 0, stream>>>(Tt, Gm2pm, Gmu, Gb2pb, Gbw, pm, pm, 0, 1);
    sink_seq(Tt, pm, 0, pm, avec, bvec, 1, stream);
    for (int ot = 1; ot < OTL; ++ot) {
        gemm_splitk_k<<<gsk, blk, 0, stream>>>(Gmt, Tt, part);
        comb_k<0><<<512, blk, 0, stream>>>(part, M, nullptr, nullptr, nullptr);
        gemm_splitk_k<<<gsk, blk, 0, stream>>>(Gbt, M, part);
        comb_k<2><<<512, blk, 0, stream>>>(part, Tt, Gm2pm, Gb2pb, nullptr);
        sink_seq(Tt, pm, 0, pm, avec, bvec, 1, stream);
    }
    // d = sum_ij (Gm2pm[i] + Gb2pb[j] - 2*(Gm T Gb^T)[i][j]) * T[i][j]
    gemm_splitk_k<<<gsk, blk, 0, stream>>>(Gmt, Tt, part);
    comb_k<0><<<512, blk, 0, stream>>>(part, M, nullptr, nullptr, nullptr);
    gemm_splitk_k<<<gsk, blk, 0, stream>>>(Gbt, M, part);
    zero_k<<<1, 1, 0, stream>>>(out);
    comb_k<3><<<256, blk, 0, stream>>>(part, Tt, Gm2pm, Gb2pb, out);
    copy_k<<<1024, blk, 0, stream>>>(out + 1, Gb, NN);
}

// Round 5
// 758.661 us; speedup vs baseline: 5.2116x; 1.1853x over previous
//
#include <hip/hip_runtime.h>
#include <math.h>

#define N_   1024
#define K_   8
#define OTL  3
#define SKL  3
#define GWBL 2
#define INVB 10.0f      /* 1/PROX_BETA */
#define EPSV 1e-16f
#define INVN (1.0f / 1024.0f)   /* exact */
#define NN   ((size_t)N_ * N_)

typedef __attribute__((ext_vector_type(8))) short short8;
typedef __attribute__((ext_vector_type(4))) float f32x4;
typedef unsigned short bfu;

__device__ __forceinline__ float b2f(bfu u) {
    unsigned x = ((unsigned)u) << 16;
    return __builtin_bit_cast(float, x);
}
__device__ __forceinline__ bfu f2b(float f) {
    unsigned u = __builtin_bit_cast(unsigned, f);
    unsigned r = u + 0x7fffu + ((u >> 16) & 1u);   // RNE (finite values only)
    return (bfu)(r >> 16);
}

/* ============ bf16 MFMA GEMM: C[m][n] = sum_k A[m][k]*B[n][k] ============
   128x128 tile, 256 thr = 4 waves (2x2), 64x64/wave, mfma 16x16x32.
   XCD affinity: z = blockIdx.x (flat%8 == bx -> all blocks of slice z on XCD z).
   EPI 0: store C bf16 | EPI 1: store C fp32 * wts[z] | EPI 2: prox in-place */
template<int EPI>
__global__ __launch_bounds__(256, 2)
void bgemm_k(const bfu* __restrict__ A, const bfu* __restrict__ B,
             void* __restrict__ Cp, size_t sA, size_t sB, size_t sC,
             const float* __restrict__ rv, const float* __restrict__ cv,
             const float* __restrict__ wts) {
    __shared__ bfu As[128 * 32];
    __shared__ bfu Bs[128 * 32];

    const int z  = blockIdx.x;               // XCD-affine batch slice
    const int bm = blockIdx.y * 128, bn = blockIdx.z * 128;
    const int tid = threadIdx.x;
    const int lane = tid & 63, wv = tid >> 6;
    const int wr = wv >> 1, wc = wv & 1;

    const bfu* Az = A + (size_t)z * sA;
    const bfu* Bz = B + (size_t)z * sB;

    const int sr = tid >> 2;          // staging row (0..63 per half)
    const int sk = (tid & 3) * 8;     // staging k-offset (elems)
    const int fr = lane & 15;
    const int ks = (lane >> 4) * 8;

    f32x4 acc[4][4];
    #pragma unroll
    for (int i = 0; i < 4; i++)
        #pragma unroll
        for (int j = 0; j < 4; j++) acc[i][j] = (f32x4)0.f;

    for (int k0 = 0; k0 < N_; k0 += 32) {
        __syncthreads();
        #pragma unroll
        for (int h = 0; h < 2; ++h) {
            const int row = sr + h * 64;
            const bfu* ga = Az + (size_t)(bm + row) * N_ + k0 + sk;
            const bfu* gb = Bz + (size_t)(bn + row) * N_ + k0 + sk;
            __builtin_amdgcn_global_load_lds(
                (const __attribute__((address_space(1))) unsigned int*)ga,
                (__attribute__((address_space(3))) unsigned int*)&As[row * 32 + sk],
                16, 0, 0);
            __builtin_amdgcn_global_load_lds(
                (const __attribute__((address_space(1))) unsigned int*)gb,
                (__attribute__((address_space(3))) unsigned int*)&Bs[row * 32 + sk],
                16, 0, 0);
        }
        __syncthreads();

        short8 af[4], bf[4];
        #pragma unroll
        for (int mi = 0; mi < 4; ++mi)
            af[mi] = *(const short8*)&As[(wr * 64 + mi * 16 + fr) * 32 + ks];
        #pragma unroll
        for (int ni = 0; ni < 4; ++ni)
            bf[ni] = *(const short8*)&Bs[(wc * 64 + ni * 16 + fr) * 32 + ks];
        #pragma unroll
        for (int mi = 0; mi < 4; ++mi)
            #pragma unroll
            for (int ni = 0; ni < 4; ++ni)
                acc[mi][ni] = __builtin_amdgcn_mfma_f32_16x16x32_bf16(
                    af[mi], bf[ni], acc[mi][ni], 0, 0, 0);
    }

    const int r0 = bm + wr * 64, c0 = bn + wc * 64;
    const int rq = (lane >> 4) * 4;   // C/D: col=lane&15, row=(lane>>4)*4+q

    if (EPI == 1) {
        float* Cz = (float*)Cp + (size_t)z * sC;
        const float w = wts[z];
        #pragma unroll
        for (int mi = 0; mi < 4; ++mi)
            #pragma unroll
            for (int ni = 0; ni < 4; ++ni)
                #pragma unroll
                for (int q = 0; q < 4; ++q)
                    Cz[(size_t)(r0 + mi * 16 + rq + q) * N_ + c0 + ni * 16 + fr]
                        = w * acc[mi][ni][q];
    } else if (EPI == 0) {
        bfu* Cz = (bfu*)Cp + (size_t)z * sC;
        #pragma unroll
        for (int mi = 0; mi < 4; ++mi)
            #pragma unroll
            for (int ni = 0; ni < 4; ++ni)
                #pragma unroll
                for (int q = 0; q < 4; ++q)
                    Cz[(size_t)(r0 + mi * 16 + rq + q) * N_ + c0 + ni * 16 + fr]
                        = f2b(acc[mi][ni][q]);
    } else {  // EPI == 2: prox in place on Tt
        bfu* Cz = (bfu*)Cp + (size_t)z * sC;
        const float* rvz = rv + z * N_;
        #pragma unroll
        for (int mi = 0; mi < 4; ++mi)
            #pragma unroll
            for (int ni = 0; ni < 4; ++ni)
                #pragma unroll
                for (int q = 0; q < 4; ++q) {
                    const int row = r0 + mi * 16 + rq + q;
                    const int col = c0 + ni * 16 + fr;
                    const float cost = rvz[col] + cv[row] - 2.f * acc[mi][ni][q];
                    const float t = b2f(Cz[(size_t)row * N_ + col]);
                    Cz[(size_t)row * N_ + col] = f2b(expf(-cost * INVB) * t);
                }
    }
}

/* ---- split-K GEMM: P[s][m][n] = sum_{k in slice s} A[m][k]*B[n][k], fp32 ----
   B-panel XCD affinity: bn from blockIdx.x. */
__global__ __launch_bounds__(256, 2)
void gemm_splitk_k(const bfu* __restrict__ A, const bfu* __restrict__ B,
                   float* __restrict__ P) {
    __shared__ bfu As[128 * 32];
    __shared__ bfu Bs[128 * 32];
    const int bn = blockIdx.x * 128;
    const int bm = blockIdx.y * 128;
    const int kbase = blockIdx.z * 256;
    const int tid = threadIdx.x;
    const int lane = tid & 63, wv = tid >> 6;
    const int wr = wv >> 1, wc = wv & 1;
    const int sr = tid >> 2, sk = (tid & 3) * 8;
    const int fr = lane & 15, ks = (lane >> 4) * 8;

    f32x4 acc[4][4];
    #pragma unroll
    for (int i = 0; i < 4; i++)
        #pragma unroll
        for (int j = 0; j < 4; j++) acc[i][j] = (f32x4)0.f;

    for (int k0 = kbase; k0 < kbase + 256; k0 += 32) {
        __syncthreads();
        #pragma unroll
        for (int h = 0; h < 2; ++h) {
            const int row = sr + h * 64;
            __builtin_amdgcn_global_load_lds(
                (const __attribute__((address_space(1))) unsigned int*)
                    (A + (size_t)(bm + row) * N_ + k0 + sk),
                (__attribute__((address_space(3))) unsigned int*)&As[row * 32 + sk],
                16, 0, 0);
            __builtin_amdgcn_global_load_lds(
                (const __attribute__((address_space(1))) unsigned int*)
                    (B + (size_t)(bn + row) * N_ + k0 + sk),
                (__attribute__((address_space(3))) unsigned int*)&Bs[row * 32 + sk],
                16, 0, 0);
        }
        __syncthreads();
        short8 af[4], bf[4];
        #pragma unroll
        for (int mi = 0; mi < 4; ++mi)
            af[mi] = *(const short8*)&As[(wr * 64 + mi * 16 + fr) * 32 + ks];
        #pragma unroll
        for (int ni = 0; ni < 4; ++ni)
            bf[ni] = *(const short8*)&Bs[(wc * 64 + ni * 16 + fr) * 32 + ks];
        #pragma unroll
        for (int mi = 0; mi < 4; ++mi)
            #pragma unroll
            for (int ni = 0; ni < 4; ++ni)
                acc[mi][ni] = __builtin_amdgcn_mfma_f32_16x16x32_bf16(
                    af[mi], bf[ni], acc[mi][ni], 0, 0, 0);
    }

    float* Pz = P + (size_t)blockIdx.z * NN;
    const int r0 = bm + wr * 64, c0 = bn + wc * 64;
    const int rq = (lane >> 4) * 4;
    #pragma unroll
    for (int mi = 0; mi < 4; ++mi)
        #pragma unroll
        for (int ni = 0; ni < 4; ++ni)
            #pragma unroll
            for (int q = 0; q < 4; ++q)
                Pz[(size_t)(r0 + mi * 16 + rq + q) * N_ + c0 + ni * 16 + fr]
                    = acc[mi][ni][q];
}

/* ---- split-K combines (row-per-block, 2 rows each) ----
   EPI 0: M = bf16(sum P), optional dout zeroing
   EPI 2: prox into Tt + emit bv[row] (first Sinkhorn b, uniform a0)
   EPI 3: distance reduce into dout */
template<int EPI>
__global__ void comb_k(const float* __restrict__ P, bfu* __restrict__ Tt,
                       const float* __restrict__ rv, const float* __restrict__ cv,
                       float* __restrict__ dout, const float* __restrict__ pb,
                       float* __restrict__ bv) {
    const int tid = threadIdx.x;
    if (EPI == 0) {
        if (dout && blockIdx.x == 0 && tid == 0) *dout = 0.f;
    }
    __shared__ float red[4];
    float bs = 0.f;
    #pragma unroll
    for (int rep = 0; rep < 2; ++rep) {
        const int row = blockIdx.x + rep * 512;
        const size_t idx = (size_t)row * N_ + tid * 4;
        float4 s = *(const float4*)(P + idx);
        #pragma unroll
        for (int sl = 1; sl < 4; ++sl) {
            float4 v = *(const float4*)(P + (size_t)sl * NN + idx);
            s.x += v.x; s.y += v.y; s.z += v.z; s.w += v.w;
        }
        if (EPI == 0) {
            bfu o[4];
            o[0] = f2b(s.x); o[1] = f2b(s.y); o[2] = f2b(s.z); o[3] = f2b(s.w);
            *(ulong1*)&Tt[idx] = *(ulong1*)o;
        } else {
            const int c = tid * 4;
            const float cvr = cv[row];
            const float4 rvc = *(const float4*)(rv + c);
            bfu t[4];
            *(ulong1*)t = *(const ulong1*)&Tt[idx];
            if (EPI == 2) {
                t[0] = f2b(expf(-(rvc.x + cvr - 2.f * s.x) * INVB) * b2f(t[0]));
                t[1] = f2b(expf(-(rvc.y + cvr - 2.f * s.y) * INVB) * b2f(t[1]));
                t[2] = f2b(expf(-(rvc.z + cvr - 2.f * s.z) * INVB) * b2f(t[2]));
                t[3] = f2b(expf(-(rvc.w + cvr - 2.f * s.w) * INVB) * b2f(t[3]));
                *(ulong1*)&Tt[idx] = *(ulong1*)t;
                // row-sum of new T for the first Sinkhorn b (a0 uniform = 1/N)
                float rs = b2f(t[0]) + b2f(t[1]) + b2f(t[2]) + b2f(t[3]);
                #pragma unroll
                for (int off = 32; off; off >>= 1) rs += __shfl_down(rs, off);
                if ((tid & 63) == 0) red[tid >> 6] = rs;
                __syncthreads();
                if (tid == 0)
                    bv[row] = pb[row] /
                        ((red[0] + red[1] + red[2] + red[3]) * INVN + EPSV);
                __syncthreads();
            } else {  // EPI 3
                bs += (rvc.x + cvr - 2.f * s.x) * b2f(t[0]);
                bs += (rvc.y + cvr - 2.f * s.y) * b2f(t[1]);
                bs += (rvc.z + cvr - 2.f * s.z) * b2f(t[2]);
                bs += (rvc.w + cvr - 2.f * s.w) * b2f(t[3]);
            }
        }
    }
    if (EPI == 3) {
        #pragma unroll
        for (int off = 32; off; off >>= 1) bs += __shfl_down(bs, off);
        if ((tid & 63) == 0) red[tid >> 6] = bs;
        __syncthreads();
        if (tid == 0) atomicAdd(dout, red[0] + red[1] + red[2] + red[3]);
    }
}

/* ============ rank-1 first OT step: prox + first Sinkhorn b fused ============
   Block covers 2 rows. Tt[z][j][i] = exp(-(c2+d2-2uw)*INVB)*ps[i]*pb[j];
   bv[z*N+j] = pb[j] / (rowsum * 1/N + eps)   (a0 uniform). */
__global__ __launch_bounds__(256)
void prox1_k(bfu* __restrict__ Tt, const float* __restrict__ c2,
             const float* __restrict__ u, const float* __restrict__ d2,
             const float* __restrict__ w, const float* __restrict__ ps,
             const float* __restrict__ pb, float* __restrict__ bv,
             int zs, int nb) {
    const int b = blockIdx.x;
    const int z  = (nb == 8) ? (b & 7) : 0;      // XCD-affine
    const int rp = (nb == 8) ? (b >> 3) : b;
    const int tid = threadIdx.x;
    const int half = tid >> 7;
    const int j = rp * 2 + half;
    const int i0 = (tid & 127) * 8;
    const float d2j = d2[j], wj = w[j], pbj = pb[j];
    const float* c2z = c2 + z * zs + i0;
    const float* uz  = u  + z * zs + i0;
    const float* psz = ps + z * zs + i0;
    bfu o[8];
    float s = 0.f;
    #pragma unroll
    for (int t = 0; t < 8; ++t) {
        const float cost = c2z[t] + d2j - 2.f * uz[t] * wj;
        o[t] = f2b(expf(-cost * INVB) * psz[t] * pbj);
        s += b2f(o[t]);
    }
    *(short8*)&Tt[((size_t)z << 20) + ((size_t)j << 10) + i0] = *(short8*)o;
    #pragma unroll
    for (int off = 32; off; off >>= 1) s += __shfl_down(s, off);
    __shared__ float red[4];
    if ((tid & 63) == 0) red[tid >> 6] = s;
    __syncthreads();
    if ((tid & 127) == 0)
        bv[z * N_ + j] = pbj / ((red[half * 2] + red[half * 2 + 1]) * INVN + EPSV);
}

/* ============ Sinkhorn kernels (z -> XCD affine) ============ */

// bv[z*N+j] = pb[j] / (dot(Tt[z][j][:], a0[z*astr..]) + eps) — wave/row
__global__ void sinkb_k(const bfu* __restrict__ Tt, const float* __restrict__ a0,
                        int astr, const float* __restrict__ pb, float* __restrict__ bv) {
    int z, jb;
    if (gridDim.y == 8) { z = blockIdx.x & 7; jb = (blockIdx.x >> 3) + (blockIdx.y << 5); }
    else                { z = 0;              jb = blockIdx.x; }
    const int wv = threadIdx.x >> 6, lane = threadIdx.x & 63;
    const int j = jb * 4 + wv;
    const bfu* Tr = Tt + (size_t)z * NN + (size_t)j * N_;
    const float* az = a0 + z * astr;
    float s = 0.f;
    for (int c = lane * 8; c < N_; c += 512) {
        bfu t[8];
        *(short8*)t = *(const short8*)&Tr[c];
        #pragma unroll
        for (int q = 0; q < 8; ++q) s += b2f(t[q]) * az[c + q];
    }
    #pragma unroll
    for (int off = 32; off; off >>= 1) s += __shfl_down(s, off);
    if (lane == 0) bv[z * N_ + j] = pb[j] / (s + EPSV);
}

// av[z*N+i] = ps[z*pstr+i] / (sum_j Tt[z][j][i]*bv[z*N+j] + eps)
// CPB=64: batched, grid (16,8). CPB=16: single-T, grid (64,1).
template<int CPB>
__global__ __launch_bounds__(1024)
void sinka_k(const bfu* __restrict__ Tt, const float* __restrict__ bv,
             const float* __restrict__ ps, int pstr, float* __restrict__ av) {
    constexpr int RG  = 1024 / CPB;
    constexpr int RPG = N_ / RG;
    int z, cb;
    if (CPB == 64) { z = blockIdx.x & 7; cb = (blockIdx.x >> 3) + (blockIdx.y << 1); }
    else           { z = 0;              cb = blockIdx.x; }
    const int cl = threadIdx.x % CPB, rg = threadIdx.x / CPB;
    const int i = cb * CPB + cl;
    const bfu* Tz = Tt + (size_t)z * NN;
    const float* bz = bv + z * N_;
    float s = 0.f;
    #pragma unroll 8
    for (int j = rg * RPG; j < rg * RPG + RPG; ++j)
        s += b2f(Tz[(size_t)j * N_ + i]) * bz[j];
    __shared__ float red[1024];
    red[rg * CPB + cl] = s;
    __syncthreads();
    #pragma unroll
    for (int h = RG / 2; h > 0; h >>= 1) {
        if (rg < h) red[rg * CPB + cl] += red[(rg + h) * CPB + cl];
        __syncthreads();
    }
    if (rg == 0) av[z * N_ + i] = ps[z * pstr + i] / (red[cl] + EPSV);
}

// Tt[z][j][i] *= av[z*N+i] * bv[z*N+j]   — grid (512, nb), no stride loop
__global__ void tupd_k(bfu* __restrict__ Tt, const float* __restrict__ av,
                       const float* __restrict__ bv, int nb) {
    int z, c;
    if (nb == 8) { z = blockIdx.x & 7; c = (blockIdx.x >> 3) + (blockIdx.y << 6); }
    else         { z = 0;              c = blockIdx.x; }
    const size_t i8 = ((size_t)z << 17) + (size_t)c * 256 + threadIdx.x;
    const size_t idx = i8 * 8;
    const int j  = (int)((idx >> 10) & (N_ - 1));
    const int i0 = (int)(idx & (N_ - 1));
    const float bj = bv[z * N_ + j];
    const float* az = av + z * N_;
    bfu t[8];
    *(short8*)t = *(const short8*)&Tt[idx];
    #pragma unroll
    for (int q = 0; q < 8; ++q) t[q] = f2b(b2f(t[q]) * az[i0 + q] * bj);
    *(short8*)&Tt[idx] = *(short8*)t;
}

/* ============ elementwise / reduction kernels ============ */

__global__ void sig2bf_k(const float* __restrict__ x, bfu* __restrict__ y, size_t n4) {
    size_t i = blockIdx.x * (size_t)blockDim.x + threadIdx.x;
    size_t st = (size_t)gridDim.x * blockDim.x;
    for (; i < n4; i += st) {
        float4 v = ((const float4*)x)[i];
        bfu o[4];
        o[0] = f2b(1.f / (1.f + expf(-v.x)));
        o[1] = f2b(1.f / (1.f + expf(-v.y)));
        o[2] = f2b(1.f / (1.f + expf(-v.z)));
        o[3] = f2b(1.f / (1.f + expf(-v.w)));
        *(ulong1*)&y[i * 4] = *(ulong1*)o;
    }
}

// Gmt = Gbt = bf16(Gm); Gb = Gm  (one pass)
__global__ void prep_gm_k(const float* __restrict__ Gm, bfu* __restrict__ Gmt,
                          bfu* __restrict__ Gbt, float* __restrict__ Gb) {
    size_t i = blockIdx.x * (size_t)blockDim.x + threadIdx.x;
    size_t st = (size_t)gridDim.x * blockDim.x;
    for (; i < NN / 4; i += st) {
        float4 v = ((const float4*)Gm)[i];
        ((float4*)Gb)[i] = v;
        bfu o[4];
        o[0] = f2b(v.x); o[1] = f2b(v.y); o[2] = f2b(v.z); o[3] = f2b(v.w);
        *(ulong1*)&Gmt[i * 4] = *(ulong1*)o;
        *(ulong1*)&Gbt[i * 4] = *(ulong1*)o;
    }
}

__global__ void copy_k(float* __restrict__ dst, const float* __restrict__ src, size_t n) {
    size_t i = blockIdx.x * (size_t)blockDim.x + threadIdx.x;
    size_t st = (size_t)gridDim.x * blockDim.x;
    for (; i < n; i += st) dst[i] = src[i];
}

// dual-output: y2[z*N+r] = sum_c sig(atoms)^2 * probs;  y1 = sum_c sig(atoms) * probs
__global__ void sqsig_mv_k(const float* __restrict__ atoms, const float* __restrict__ probs,
                           float* __restrict__ y2, float* __restrict__ y1) {
    int z = blockIdx.y;
    int wv = threadIdx.x >> 6, lane = threadIdx.x & 63;
    int r = blockIdx.x * 4 + wv;
    const float* Ar = atoms + (size_t)z * NN + (size_t)r * N_;
    const float* pz = probs + z * N_;
    float s2 = 0.f, s1 = 0.f;
    for (int c = lane * 4; c < N_; c += 256) {
        float4 v = *(const float4*)(Ar + c);
        float4 p = *(const float4*)(pz + c);
        float sx = 1.f / (1.f + expf(-v.x)), sy = 1.f / (1.f + expf(-v.y));
        float sz = 1.f / (1.f + expf(-v.z)), sw = 1.f / (1.f + expf(-v.w));
        s2 += sx * sx * p.x + sy * sy * p.y + sz * sz * p.z + sw * sw * p.w;
        s1 += sx * p.x + sy * p.y + sz * p.z + sw * p.w;
    }
    #pragma unroll
    for (int off = 32; off; off >>= 1) {
        s2 += __shfl_down(s2, off);
        s1 += __shfl_down(s1, off);
    }
    if (lane == 0) { y2[z * N_ + r] = s2; y1[z * N_ + r] = s1; }
}

// dual-output fp32: y2[r] = sum_c A[r][c]^2 p[c];  y1[r] = sum_c A[r][c] p[c]
__global__ void sq_mv_k(const float* __restrict__ A, const float* __restrict__ p,
                        float* __restrict__ y2, float* __restrict__ y1) {
    int wv = threadIdx.x >> 6, lane = threadIdx.x & 63;
    int r = blockIdx.x * 4 + wv;
    const float* Ar = A + (size_t)r * N_;
    float s2 = 0.f, s1 = 0.f;
    for (int c = lane * 4; c < N_; c += 256) {
        float4 v = *(const float4*)(Ar + c);
        float4 pv = *(const float4*)(p + c);
        s2 += v.x * v.x * pv.x + v.y * v.y * pv.y + v.z * v.z * pv.z + v.w * v.w * pv.w;
        s1 += v.x * pv.x + v.y * pv.y + v.z * pv.z + v.w * pv.w;
    }
    #pragma unroll
    for (int off = 32; off; off >>= 1) {
        s2 += __shfl_down(s2, off);
        s1 += __shfl_down(s1, off);
    }
    if (lane == 0) { y2[r] = s2; y1[r] = s1; }
}

// Gb[i][j] = (sum_z part[z][i][j]) / (pm[i]*pm[j]);  Gbt = bf16(Gb)
__global__ void reduce8_k(const float* __restrict__ part, const float* __restrict__ pm,
                          float* __restrict__ Gb, bfu* __restrict__ Gbt) {
    size_t st = (size_t)gridDim.x * blockDim.x;
    for (size_t i4 = blockIdx.x * (size_t)blockDim.x + threadIdx.x; i4 < NN / 4; i4 += st) {
        size_t idx = i4 * 4;
        int i = (int)(idx >> 10), j = (int)(idx & (N_ - 1));
        float pi = pm[i];
        float4 pj = *(const float4*)(pm + j);
        float4 s = *(const float4*)(part + idx);
        #pragma unroll
        for (int z = 1; z < K_; ++z) {
            float4 v = *(const float4*)(part + (size_t)z * NN + idx);
            s.x += v.x; s.y += v.y; s.z += v.z; s.w += v.w;
        }
        s.x /= pi * pj.x; s.y /= pi * pj.y; s.z /= pi * pj.z; s.w /= pi * pj.w;
        *(float4*)(Gb + idx) = s;
        bfu o[4];
        o[0] = f2b(s.x); o[1] = f2b(s.y); o[2] = f2b(s.z); o[3] = f2b(s.w);
        *(ulong1*)&Gbt[idx] = *(ulong1*)o;
    }
}

/* ============ host sequence ============ */

// Sinkhorn tail given bv already computed (b1 fused into producer):
// a1, b2, a2, b3, a3, tupd
template<int NB>
static inline void sink_tail(bfu* Tt, const float* ps, int pstr, const float* pm,
                             float* avec, float* bvec, hipStream_t stream) {
    constexpr int CPB = (NB == 8) ? 64 : 16;
    const dim3 blk(256);
    const dim3 ga((NB == 8) ? 16 : 64, (NB == 8) ? 8 : 1);
    const dim3 gb(256, NB);
    sinka_k<CPB><<<ga, dim3(1024), 0, stream>>>(Tt, bvec, ps, pstr, avec);
    for (int s = 1; s < SKL; ++s) {
        sinkb_k<<<gb, blk, 0, stream>>>(Tt, avec, N_, pm, bvec);
        sinka_k<CPB><<<ga, dim3(1024), 0, stream>>>(Tt, bvec, ps, pstr, avec);
    }
    tupd_k<<<dim3(512, NB), blk, 0, stream>>>(Tt, avec, bvec, NB);
}

extern "C" void kernel_launch(void* const* d_in, const int* in_sizes, int n_in,
                              void* d_out, int out_size, void* d_ws, size_t ws_size,
                              hipStream_t stream) {
    const float* Gm    = (const float*)d_in[0];
    const float* pm    = (const float*)d_in[1];
    const float* atoms = (const float*)d_in[2];
    const float* probs = (const float*)d_in[3];
    const float* wts   = (const float*)d_in[4];
    float* out = (float*)d_out;                  // [0]=d_fgw, [1..]=G_bary (fp32)

    char* base = (char*)d_ws;
    bfu*   Gkt  = (bfu*)base;                    base += K_ * NN * 2;
    bfu*   Tt   = (bfu*)base;                    base += K_ * NN * 2;
    bfu*   M    = (bfu*)base;                    base += K_ * NN * 2;
    float* part = (float*)base;                  base += K_ * NN * 4;
    float* Gb   = (float*)base;                  base += NN * 4;
    bfu*   Gbt  = (bfu*)base;                    base += NN * 2;
    bfu*   Gmt  = (bfu*)base;                    base += NN * 2;
    float* Gk2ps = (float*)base;                 base += K_ * N_ * 4;
    float* Gku   = (float*)base;                 base += K_ * N_ * 4;
    float* Gm2pm = (float*)base;                 base += N_ * 4;
    float* Gmu   = (float*)base;                 base += N_ * 4;
    float* Gb2pb = (float*)base;                 base += N_ * 4;
    float* Gbw   = (float*)base;                 base += N_ * 4;
    float* avec  = (float*)base;                 base += K_ * N_ * 4;
    float* bvec  = (float*)base;                 base += K_ * N_ * 4;

    const dim3 blk(256);
    const dim3 g8(8, 8, 8);      // (z, m-tile, n-tile): z -> XCD
    const dim3 gsk(8, 8, 4);     // (n-tile, m-tile, k-slice): n -> XCD

    // setup
    sig2bf_k<<<2048, blk, 0, stream>>>(atoms, Gkt, K_ * NN / 4);
    sqsig_mv_k<<<dim3(N_ / 4, K_), blk, 0, stream>>>(atoms, probs, Gk2ps, Gku);
    sq_mv_k<<<dim3(N_ / 4, 1), blk, 0, stream>>>(Gm, pm, Gm2pm, Gmu);
    prep_gm_k<<<1024, blk, 0, stream>>>(Gm, Gmt, Gbt, Gb);

    for (int it = 0; it < GWBL; ++it) {
        sq_mv_k<<<dim3(N_ / 4, 1), blk, 0, stream>>>(Gb, pm, Gb2pb, Gbw);
        // OT step 0: rank-1 analytic prox + fused first-b
        prox1_k<<<512 * K_, blk, 0, stream>>>(Tt, Gk2ps, Gku, Gb2pb, Gbw,
                                              probs, pm, bvec, N_, K_);
        sink_tail<K_>(Tt, probs, N_, pm, avec, bvec, stream);
        for (int ot = 1; ot < OTL; ++ot) {
            // M[i][n] = sum_k Gk[i][k] * Tt[n][k]          (= Gs @ T)
            bgemm_k<0><<<g8, blk, 0, stream>>>(Gkt, Tt, M, NN, NN, NN,
                nullptr, nullptr, nullptr);
            // Tt[j][i] = exp(-(Gk2ps[i]+Gb2pb[j]-2*(Gb M^T)[j][i])*INVB) * Tt[j][i]
            bgemm_k<2><<<g8, blk, 0, stream>>>(Gbt, M, Tt, 0, NN, NN,
                Gk2ps, Gb2pb, nullptr);
            sinkb_k<<<dim3(256, K_), blk, 0, stream>>>(Tt, probs, N_, pm, bvec);
            sink_tail<K_>(Tt, probs, N_, pm, avec, bvec, stream);
        }
        // GTt[j][i'] = sum_k Tt[j][k]*Gk[i'][k]            (= (Gk @ T)^T)
        bgemm_k<0><<<g8, blk, 0, stream>>>(Tt, Gkt, M, NN, NN, NN,
            nullptr, nullptr, nullptr);
        // part[z][i][j] = w_z * sum_n Tt[z][i][n]*GTt[z][j][n]  (= w_z T^T G T)
        bgemm_k<1><<<g8, blk, 0, stream>>>(Tt, M, part, NN, NN, NN,
            nullptr, nullptr, wts);
        reduce8_k<<<1024, blk, 0, stream>>>(part, pm, Gb, Gbt);
    }

    // ---- final fgwd(Gm, pm, Gb, pm) ----
    sq_mv_k<<<dim3(N_ / 4, 1), blk, 0, stream>>>(Gb, pm, Gb2pb, Gbw);
    prox1_k<<<512, blk, 0, stream>>>(Tt, Gm2pm, Gmu, Gb2pb, Gbw, pm, pm, bvec, 0, 1);
    sink_tail<1>(Tt, pm, 0, pm, avec, bvec, stream);
    for (int ot = 1; ot < OTL; ++ot) {
        gemm_splitk_k<<<gsk, blk, 0, stream>>>(Gmt, Tt, part);
        comb_k<0><<<512, blk, 0, stream>>>(part, M, nullptr, nullptr,
                                           nullptr, nullptr, nullptr);
        gemm_splitk_k<<<gsk, blk, 0, stream>>>(Gbt, M, part);
        comb_k<2><<<512, blk, 0, stream>>>(part, Tt, Gm2pm, Gb2pb,
                                           nullptr, pm, bvec);
        sink_tail<1>(Tt, pm, 0, pm, avec, bvec, stream);
    }
    // d = sum_ij (Gm2pm[i] + Gb2pb[j] - 2*(Gm T Gb^T)[i][j]) * T[i][j]
    gemm_splitk_k<<<gsk, blk, 0, stream>>>(Gmt, Tt, part);
    comb_k<0><<<512, blk, 0, stream>>>(part, M, nullptr, nullptr,
                                       out /* zero d */, nullptr, nullptr);
    gemm_splitk_k<<<gsk, blk, 0, stream>>>(Gbt, M, part);
    comb_k<3><<<512, blk, 0, stream>>>(part, Tt, Gm2pm, Gb2pb, out, nullptr, nullptr);
    copy_k<<<1024, blk, 0, stream>>>(out + 1, Gb, NN);
}

// Round 6
// 684.255 us; speedup vs baseline: 5.7784x; 1.1087x over previous
//
#include <hip/hip_runtime.h>
#include <math.h>

#define N_   1024
#define K_   8
#define OTL  3
#define SKL  3
#define GWBL 2
#define INVB 10.0f      /* 1/PROX_BETA */
#define EPSV 1e-16f
#define INVN (1.0f / 1024.0f)   /* exact: pm = probs = 1/N */
#define NN   ((size_t)N_ * N_)

typedef __attribute__((ext_vector_type(8))) short short8;
typedef __attribute__((ext_vector_type(4))) float f32x4;
typedef unsigned short bfu;

__device__ __forceinline__ float b2f(bfu u) {
    unsigned x = ((unsigned)u) << 16;
    return __builtin_bit_cast(float, x);
}
__device__ __forceinline__ bfu f2b(float f) {
    unsigned u = __builtin_bit_cast(unsigned, f);
    unsigned r = u + 0x7fffu + ((u >> 16) & 1u);   // RNE (finite values only)
    return (bfu)(r >> 16);
}

/* ============ bf16 MFMA GEMM: C[m][n] = sum_k A[m][k]*B[n][k] ============
   128x128 tile, 256 thr = 4 waves (2x2), 64x64/wave, mfma 16x16x32.
   XCD affinity: z = blockIdx.x.
   EPI 0: store C bf16; if rs: blocks (y==0,z==0) zero rs[z*N..] (for next EPI2)
   EPI 1: store C fp32 * wts[z]
   EPI 2: prox in-place + atomic row-sums of new T into rs                  */
template<int EPI>
__global__ __launch_bounds__(256, 2)
void bgemm_k(const bfu* __restrict__ A, const bfu* __restrict__ B,
             void* __restrict__ Cp, size_t sA, size_t sB, size_t sC,
             const float* __restrict__ rv, const float* __restrict__ cv,
             const float* __restrict__ wts, float* __restrict__ rs) {
    __shared__ bfu As[128 * 32];
    __shared__ bfu Bs[128 * 32];

    const int z  = blockIdx.x;               // XCD-affine batch slice
    const int bm = blockIdx.y * 128, bn = blockIdx.z * 128;
    const int tid = threadIdx.x;
    const int lane = tid & 63, wv = tid >> 6;
    const int wr = wv >> 1, wc = wv & 1;

    if (EPI == 0) {   // zero next prox's row-sum accumulator (1024 floats/z)
        if (rs && blockIdx.y == 0 && blockIdx.z == 0) {
            float4 zf = {0.f, 0.f, 0.f, 0.f};
            *(float4*)&rs[z * N_ + tid * 4] = zf;
        }
    }

    const bfu* Az = A + (size_t)z * sA;
    const bfu* Bz = B + (size_t)z * sB;

    const int sr = tid >> 2;          // staging row (0..63 per half)
    const int sk = (tid & 3) * 8;     // staging k-offset (elems)
    const int fr = lane & 15;
    const int ks = (lane >> 4) * 8;

    f32x4 acc[4][4];
    #pragma unroll
    for (int i = 0; i < 4; i++)
        #pragma unroll
        for (int j = 0; j < 4; j++) acc[i][j] = (f32x4)0.f;

    for (int k0 = 0; k0 < N_; k0 += 32) {
        __syncthreads();
        #pragma unroll
        for (int h = 0; h < 2; ++h) {
            const int row = sr + h * 64;
            const bfu* ga = Az + (size_t)(bm + row) * N_ + k0 + sk;
            const bfu* gb = Bz + (size_t)(bn + row) * N_ + k0 + sk;
            __builtin_amdgcn_global_load_lds(
                (const __attribute__((address_space(1))) unsigned int*)ga,
                (__attribute__((address_space(3))) unsigned int*)&As[row * 32 + sk],
                16, 0, 0);
            __builtin_amdgcn_global_load_lds(
                (const __attribute__((address_space(1))) unsigned int*)gb,
                (__attribute__((address_space(3))) unsigned int*)&Bs[row * 32 + sk],
                16, 0, 0);
        }
        __syncthreads();

        short8 af[4], bf[4];
        #pragma unroll
        for (int mi = 0; mi < 4; ++mi)
            af[mi] = *(const short8*)&As[(wr * 64 + mi * 16 + fr) * 32 + ks];
        #pragma unroll
        for (int ni = 0; ni < 4; ++ni)
            bf[ni] = *(const short8*)&Bs[(wc * 64 + ni * 16 + fr) * 32 + ks];
        #pragma unroll
        for (int mi = 0; mi < 4; ++mi)
            #pragma unroll
            for (int ni = 0; ni < 4; ++ni)
                acc[mi][ni] = __builtin_amdgcn_mfma_f32_16x16x32_bf16(
                    af[mi], bf[ni], acc[mi][ni], 0, 0, 0);
    }

    const int r0 = bm + wr * 64, c0 = bn + wc * 64;
    const int rq = (lane >> 4) * 4;   // C/D: col=lane&15, row=(lane>>4)*4+q

    if (EPI == 1) {
        float* Cz = (float*)Cp + (size_t)z * sC;
        const float w = wts[z];
        #pragma unroll
        for (int mi = 0; mi < 4; ++mi)
            #pragma unroll
            for (int ni = 0; ni < 4; ++ni)
                #pragma unroll
                for (int q = 0; q < 4; ++q)
                    Cz[(size_t)(r0 + mi * 16 + rq + q) * N_ + c0 + ni * 16 + fr]
                        = w * acc[mi][ni][q];
    } else if (EPI == 0) {
        bfu* Cz = (bfu*)Cp + (size_t)z * sC;
        #pragma unroll
        for (int mi = 0; mi < 4; ++mi)
            #pragma unroll
            for (int ni = 0; ni < 4; ++ni)
                #pragma unroll
                for (int q = 0; q < 4; ++q)
                    Cz[(size_t)(r0 + mi * 16 + rq + q) * N_ + c0 + ni * 16 + fr]
                        = f2b(acc[mi][ni][q]);
    } else {  // EPI == 2: prox in place on Tt + row-sum atomics
        bfu* Cz = (bfu*)Cp + (size_t)z * sC;
        const float* rvz = rv + z * N_;
        float rsum[4][4];
        #pragma unroll
        for (int mi = 0; mi < 4; ++mi)
            #pragma unroll
            for (int q = 0; q < 4; ++q) rsum[mi][q] = 0.f;
        #pragma unroll
        for (int mi = 0; mi < 4; ++mi)
            #pragma unroll
            for (int ni = 0; ni < 4; ++ni)
                #pragma unroll
                for (int q = 0; q < 4; ++q) {
                    const int row = r0 + mi * 16 + rq + q;
                    const int col = c0 + ni * 16 + fr;
                    const float cost = rvz[col] + cv[row] - 2.f * acc[mi][ni][q];
                    const float t = b2f(Cz[(size_t)row * N_ + col]);
                    const bfu tn = f2b(expf(-cost * INVB) * t);
                    Cz[(size_t)row * N_ + col] = tn;
                    rsum[mi][q] += b2f(tn);
                }
        // reduce over the 16 fr-lanes (cols), atomicAdd one partial per row
        #pragma unroll
        for (int mi = 0; mi < 4; ++mi)
            #pragma unroll
            for (int q = 0; q < 4; ++q) {
                float v = rsum[mi][q];
                v += __shfl_xor(v, 1);
                v += __shfl_xor(v, 2);
                v += __shfl_xor(v, 4);
                v += __shfl_xor(v, 8);
                if (fr == 0)
                    atomicAdd(&rs[z * N_ + r0 + mi * 16 + rq + q], v);
            }
    }
}

/* ---- split-K GEMM: P[s][m][n] = sum_{k in slice s} A[m][k]*B[n][k], fp32 ---- */
__global__ __launch_bounds__(256, 2)
void gemm_splitk_k(const bfu* __restrict__ A, const bfu* __restrict__ B,
                   float* __restrict__ P) {
    __shared__ bfu As[128 * 32];
    __shared__ bfu Bs[128 * 32];
    const int bn = blockIdx.x * 128;
    const int bm = blockIdx.y * 128;
    const int kbase = blockIdx.z * 256;
    const int tid = threadIdx.x;
    const int lane = tid & 63, wv = tid >> 6;
    const int wr = wv >> 1, wc = wv & 1;
    const int sr = tid >> 2, sk = (tid & 3) * 8;
    const int fr = lane & 15, ks = (lane >> 4) * 8;

    f32x4 acc[4][4];
    #pragma unroll
    for (int i = 0; i < 4; i++)
        #pragma unroll
        for (int j = 0; j < 4; j++) acc[i][j] = (f32x4)0.f;

    for (int k0 = kbase; k0 < kbase + 256; k0 += 32) {
        __syncthreads();
        #pragma unroll
        for (int h = 0; h < 2; ++h) {
            const int row = sr + h * 64;
            __builtin_amdgcn_global_load_lds(
                (const __attribute__((address_space(1))) unsigned int*)
                    (A + (size_t)(bm + row) * N_ + k0 + sk),
                (__attribute__((address_space(3))) unsigned int*)&As[row * 32 + sk],
                16, 0, 0);
            __builtin_amdgcn_global_load_lds(
                (const __attribute__((address_space(1))) unsigned int*)
                    (B + (size_t)(bn + row) * N_ + k0 + sk),
                (__attribute__((address_space(3))) unsigned int*)&Bs[row * 32 + sk],
                16, 0, 0);
        }
        __syncthreads();
        short8 af[4], bf[4];
        #pragma unroll
        for (int mi = 0; mi < 4; ++mi)
            af[mi] = *(const short8*)&As[(wr * 64 + mi * 16 + fr) * 32 + ks];
        #pragma unroll
        for (int ni = 0; ni < 4; ++ni)
            bf[ni] = *(const short8*)&Bs[(wc * 64 + ni * 16 + fr) * 32 + ks];
        #pragma unroll
        for (int mi = 0; mi < 4; ++mi)
            #pragma unroll
            for (int ni = 0; ni < 4; ++ni)
                acc[mi][ni] = __builtin_amdgcn_mfma_f32_16x16x32_bf16(
                    af[mi], bf[ni], acc[mi][ni], 0, 0, 0);
    }

    float* Pz = P + (size_t)blockIdx.z * NN;
    const int r0 = bm + wr * 64, c0 = bn + wc * 64;
    const int rq = (lane >> 4) * 4;
    #pragma unroll
    for (int mi = 0; mi < 4; ++mi)
        #pragma unroll
        for (int ni = 0; ni < 4; ++ni)
            #pragma unroll
            for (int q = 0; q < 4; ++q)
                Pz[(size_t)(r0 + mi * 16 + rq + q) * N_ + c0 + ni * 16 + fr]
                    = acc[mi][ni][q];
}

/* ---- split-K combines (row-per-block, 2 rows each) ----
   EPI 0: M = bf16(sum P), optional dout zeroing
   EPI 2: prox into Tt + emit bv[row] (first Sinkhorn b, uniform a0)
   EPI 3: distance reduce into dout */
template<int EPI>
__global__ void comb_k(const float* __restrict__ P, bfu* __restrict__ Tt,
                       const float* __restrict__ rv, const float* __restrict__ cv,
                       float* __restrict__ dout, const float* __restrict__ pb,
                       float* __restrict__ bv) {
    const int tid = threadIdx.x;
    if (EPI == 0) {
        if (dout && blockIdx.x == 0 && tid == 0) *dout = 0.f;
    }
    __shared__ float red[4];
    float bs = 0.f;
    #pragma unroll
    for (int rep = 0; rep < 2; ++rep) {
        const int row = blockIdx.x + rep * 512;
        const size_t idx = (size_t)row * N_ + tid * 4;
        float4 s = *(const float4*)(P + idx);
        #pragma unroll
        for (int sl = 1; sl < 4; ++sl) {
            float4 v = *(const float4*)(P + (size_t)sl * NN + idx);
            s.x += v.x; s.y += v.y; s.z += v.z; s.w += v.w;
        }
        if (EPI == 0) {
            bfu o[4];
            o[0] = f2b(s.x); o[1] = f2b(s.y); o[2] = f2b(s.z); o[3] = f2b(s.w);
            *(ulong1*)&Tt[idx] = *(ulong1*)o;
        } else {
            const int c = tid * 4;
            const float cvr = cv[row];
            const float4 rvc = *(const float4*)(rv + c);
            bfu t[4];
            *(ulong1*)t = *(const ulong1*)&Tt[idx];
            if (EPI == 2) {
                t[0] = f2b(expf(-(rvc.x + cvr - 2.f * s.x) * INVB) * b2f(t[0]));
                t[1] = f2b(expf(-(rvc.y + cvr - 2.f * s.y) * INVB) * b2f(t[1]));
                t[2] = f2b(expf(-(rvc.z + cvr - 2.f * s.z) * INVB) * b2f(t[2]));
                t[3] = f2b(expf(-(rvc.w + cvr - 2.f * s.w) * INVB) * b2f(t[3]));
                *(ulong1*)&Tt[idx] = *(ulong1*)t;
                float rsm = b2f(t[0]) + b2f(t[1]) + b2f(t[2]) + b2f(t[3]);
                #pragma unroll
                for (int off = 32; off; off >>= 1) rsm += __shfl_down(rsm, off);
                if ((tid & 63) == 0) red[tid >> 6] = rsm;
                __syncthreads();
                if (tid == 0)
                    bv[row] = pb[row] /
                        ((red[0] + red[1] + red[2] + red[3]) * INVN + EPSV);
                __syncthreads();
            } else {  // EPI 3
                bs += (rvc.x + cvr - 2.f * s.x) * b2f(t[0]);
                bs += (rvc.y + cvr - 2.f * s.y) * b2f(t[1]);
                bs += (rvc.z + cvr - 2.f * s.z) * b2f(t[2]);
                bs += (rvc.w + cvr - 2.f * s.w) * b2f(t[3]);
            }
        }
    }
    if (EPI == 3) {
        #pragma unroll
        for (int off = 32; off; off >>= 1) bs += __shfl_down(bs, off);
        if ((tid & 63) == 0) red[tid >> 6] = bs;
        __syncthreads();
        if (tid == 0) atomicAdd(dout, red[0] + red[1] + red[2] + red[3]);
    }
}

/* ============ rank-1 first OT step: prox + first Sinkhorn b fused ============ */
__global__ __launch_bounds__(256)
void prox1_k(bfu* __restrict__ Tt, const float* __restrict__ c2,
             const float* __restrict__ u, const float* __restrict__ d2,
             const float* __restrict__ w, const float* __restrict__ ps,
             const float* __restrict__ pb, float* __restrict__ bv,
             int zs, int nb) {
    const int b = blockIdx.x;
    const int z  = (nb == 8) ? (b & 7) : 0;      // XCD-affine
    const int rp = (nb == 8) ? (b >> 3) : b;
    const int tid = threadIdx.x;
    const int half = tid >> 7;
    const int j = rp * 2 + half;
    const int i0 = (tid & 127) * 8;
    const float d2j = d2[j], wj = w[j], pbj = pb[j];
    const float* c2z = c2 + z * zs + i0;
    const float* uz  = u  + z * zs + i0;
    const float* psz = ps + z * zs + i0;
    bfu o[8];
    float s = 0.f;
    #pragma unroll
    for (int t = 0; t < 8; ++t) {
        const float cost = c2z[t] + d2j - 2.f * uz[t] * wj;
        o[t] = f2b(expf(-cost * INVB) * psz[t] * pbj);
        s += b2f(o[t]);
    }
    *(short8*)&Tt[((size_t)z << 20) + ((size_t)j << 10) + i0] = *(short8*)o;
    #pragma unroll
    for (int off = 32; off; off >>= 1) s += __shfl_down(s, off);
    __shared__ float red[4];
    if ((tid & 63) == 0) red[tid >> 6] = s;
    __syncthreads();
    if ((tid & 127) == 0)
        bv[z * N_ + j] = pbj / ((red[half * 2] + red[half * 2 + 1]) * INVN + EPSV);
}

/* ============ Sinkhorn kernels (z -> XCD affine) ============ */

// bv[z*N+j] = pb[j] / (dot(Tt[z][j][:], a0[z*N..]) + eps) — wave/row
__global__ void sinkb_k(const bfu* __restrict__ Tt, const float* __restrict__ a0,
                        const float* __restrict__ pb, float* __restrict__ bv) {
    int z, jb;
    if (gridDim.y == 8) { z = blockIdx.x & 7; jb = (blockIdx.x >> 3) + (blockIdx.y << 5); }
    else                { z = 0;              jb = blockIdx.x; }
    const int wv = threadIdx.x >> 6, lane = threadIdx.x & 63;
    const int j = jb * 4 + wv;
    const bfu* Tr = Tt + (size_t)z * NN + (size_t)j * N_;
    const float* az = a0 + z * N_;
    float s = 0.f;
    for (int c = lane * 8; c < N_; c += 512) {
        bfu t[8];
        *(short8*)t = *(const short8*)&Tr[c];
        #pragma unroll
        for (int q = 0; q < 8; ++q) s += b2f(t[q]) * az[c + q];
    }
    #pragma unroll
    for (int off = 32; off; off >>= 1) s += __shfl_down(s, off);
    if (lane == 0) bv[z * N_ + j] = pb[j] / (s + EPSV);
}

/* column pass: av[z*N+i] = ps[..]/(sum_j Tt[z][j][i]*b[j] + eps)
   RS=1: b computed in prologue from row-sums rs (a0 uniform)
   TUPD=1: after reduction, rescale own column stripe T[j][i] *= av_i*b[j]   */
template<int NB, int RS, int TUPD>
__global__ __launch_bounds__(1024)
void sinka_k(bfu* __restrict__ Tt, const float* __restrict__ bvin,
             const float* __restrict__ rs, const float* __restrict__ ps, int pstr,
             float* __restrict__ av) {
    constexpr int CPB = (NB == 8) ? 32 : 16;
    constexpr int RG  = 1024 / CPB;          // 32 or 64
    constexpr int RPG = N_ / RG;             // 32 or 16
    int z, cb;
    if (NB == 8) { z = blockIdx.x & 7; cb = blockIdx.x >> 3; }   // 256 blocks
    else         { z = 0;              cb = blockIdx.x; }        // 64 blocks
    const int tid = threadIdx.x;
    const int cl = tid % CPB, rg = tid / CPB;
    const int i = cb * CPB + cl;
    bfu* Tz = Tt + (size_t)z * NN;

    __shared__ float bvs[1024];
    __shared__ float red[1024];
    if (RS) bvs[tid] = INVN / (rs[z * N_ + tid] * INVN + EPSV);
    else    bvs[tid] = bvin[z * N_ + tid];
    __syncthreads();

    float s = 0.f;
    const int j0 = rg * RPG;
    #pragma unroll 8
    for (int j = j0; j < j0 + RPG; ++j)
        s += b2f(Tz[(size_t)j * N_ + i]) * bvs[j];
    red[tid] = s;
    __syncthreads();
    #pragma unroll
    for (int h = RG / 2; h > 0; h >>= 1) {
        if (rg < h) red[rg * CPB + cl] += red[(rg + h) * CPB + cl];
        __syncthreads();
    }
    const float avi = ps[z * pstr + i] / (red[cl] + EPSV);
    if (!TUPD) {
        if (rg == 0) av[z * N_ + i] = avi;
    } else {
        // fused tupd: rescale own column stripe (L2-hot re-read)
        for (int j = j0; j < j0 + RPG; ++j) {
            const size_t o = (size_t)j * N_ + i;
            Tz[o] = f2b(b2f(Tz[o]) * avi * bvs[j]);
        }
    }
}

/* ============ fused prep kernels ============ */

// SIG=1: atoms->sigmoid->Gkt + row moments; SIG=0: Gm->Gmt + row moments
template<int SIG>
__global__ void prep_k(const float* __restrict__ X, bfu* __restrict__ Y,
                       float* __restrict__ y2, float* __restrict__ y1) {
    const int z = blockIdx.y;
    const int wv = threadIdx.x >> 6, lane = threadIdx.x & 63;
    const int r = blockIdx.x * 4 + wv;
    const float* Xr = X + (size_t)z * NN + (size_t)r * N_;
    bfu* Yr = Y + (size_t)z * NN + (size_t)r * N_;
    float s2 = 0.f, s1 = 0.f;
    for (int c = lane * 4; c < N_; c += 256) {
        float4 v = *(const float4*)(Xr + c);
        if (SIG) {
            v.x = 1.f / (1.f + expf(-v.x));
            v.y = 1.f / (1.f + expf(-v.y));
            v.z = 1.f / (1.f + expf(-v.z));
            v.w = 1.f / (1.f + expf(-v.w));
        }
        bfu o[4];
        o[0] = f2b(v.x); o[1] = f2b(v.y); o[2] = f2b(v.z); o[3] = f2b(v.w);
        *(ulong1*)&Yr[c] = *(ulong1*)o;
        s2 += v.x * v.x + v.y * v.y + v.z * v.z + v.w * v.w;
        s1 += v.x + v.y + v.z + v.w;
    }
    #pragma unroll
    for (int off = 32; off; off >>= 1) {
        s2 += __shfl_down(s2, off);
        s1 += __shfl_down(s1, off);
    }
    if (lane == 0) {
        y2[z * N_ + r] = s2 * INVN;
        y1[z * N_ + r] = s1 * INVN;
    }
}

/* reduce8 (row-per-block): Gb_row = sum_z part[z]·N²; writes Gbt, row moments
   (Gb2pb, Gbw) for the next prox, and optionally fp32 G_bary into out1. */
__global__ void reduce8_k(const float* __restrict__ part, bfu* __restrict__ Gbt,
                          float* __restrict__ d2, float* __restrict__ w,
                          float* __restrict__ out1) {
    const int tid = threadIdx.x;
    __shared__ float wred[2][8];
    #pragma unroll
    for (int rep = 0; rep < 2; ++rep) {
        const int row = blockIdx.x + rep * 512;
        const size_t idx = (size_t)row * N_ + tid * 4;
        float4 s = *(const float4*)(part + idx);
        #pragma unroll
        for (int sl = 1; sl < K_; ++sl) {
            float4 v = *(const float4*)(part + (size_t)sl * NN + idx);
            s.x += v.x; s.y += v.y; s.z += v.z; s.w += v.w;
        }
        const float sc = 1048576.f;   // N^2 (pm uniform: / (1/N * 1/N))
        s.x *= sc; s.y *= sc; s.z *= sc; s.w *= sc;
        bfu o[4];
        o[0] = f2b(s.x); o[1] = f2b(s.y); o[2] = f2b(s.z); o[3] = f2b(s.w);
        *(ulong1*)&Gbt[idx] = *(ulong1*)o;
        if (out1) {   // out+1 is only 4B-aligned: scalar stores
            out1[idx + 0] = s.x; out1[idx + 1] = s.y;
            out1[idx + 2] = s.z; out1[idx + 3] = s.w;
        }
        float r2 = s.x * s.x + s.y * s.y + s.z * s.z + s.w * s.w;
        float r1 = s.x + s.y + s.z + s.w;
        #pragma unroll
        for (int off = 32; off; off >>= 1) {
            r2 += __shfl_down(r2, off);
            r1 += __shfl_down(r1, off);
        }
        if ((tid & 63) == 0) {
            wred[0][(tid >> 6) * 2]     = r2;
            wred[0][(tid >> 6) * 2 + 1] = r1;
        }
        __syncthreads();
        if (tid == 0) {
            d2[row] = (wred[0][0] + wred[0][2] + wred[0][4] + wred[0][6]) * INVN;
            w[row]  = (wred[0][1] + wred[0][3] + wred[0][5] + wred[0][7]) * INVN;
        }
        __syncthreads();
    }
}

/* ============ host sequence ============ */

// b1 already available (bvec if RS1==0, rs row-sums if RS1==1):
// a1, b2, a2, b3, a3+tupd
template<int NB, int RS1>
static inline void sink_tail(bfu* Tt, const float* ps, int pstr, const float* pm,
                             float* avec, float* bvec, float* rs, hipStream_t stream) {
    const dim3 ga((NB == 8) ? 256 : 64);
    const dim3 gb(256, NB);
    const dim3 blk(256);
    sinka_k<NB, RS1, 0><<<ga, dim3(1024), 0, stream>>>(Tt, bvec, rs, ps, pstr, avec);
    sinkb_k<<<gb, blk, 0, stream>>>(Tt, avec, pm, bvec);
    sinka_k<NB, 0, 0><<<ga, dim3(1024), 0, stream>>>(Tt, bvec, rs, ps, pstr, avec);
    sinkb_k<<<gb, blk, 0, stream>>>(Tt, avec, pm, bvec);
    sinka_k<NB, 0, 1><<<ga, dim3(1024), 0, stream>>>(Tt, bvec, rs, ps, pstr, avec);
}

extern "C" void kernel_launch(void* const* d_in, const int* in_sizes, int n_in,
                              void* d_out, int out_size, void* d_ws, size_t ws_size,
                              hipStream_t stream) {
    const float* Gm    = (const float*)d_in[0];
    const float* pm    = (const float*)d_in[1];
    const float* atoms = (const float*)d_in[2];
    const float* probs = (const float*)d_in[3];
    const float* wts   = (const float*)d_in[4];
    float* out = (float*)d_out;                  // [0]=d_fgw, [1..]=G_bary (fp32)

    char* base = (char*)d_ws;
    bfu*   Gkt  = (bfu*)base;                    base += K_ * NN * 2;
    bfu*   Tt   = (bfu*)base;                    base += K_ * NN * 2;
    bfu*   M    = (bfu*)base;                    base += K_ * NN * 2;
    float* part = (float*)base;                  base += K_ * NN * 4;
    bfu*   Gbt  = (bfu*)base;                    base += NN * 2;
    bfu*   Gmt  = (bfu*)base;                    base += NN * 2;
    float* Gk2ps = (float*)base;                 base += K_ * N_ * 4;
    float* Gku   = (float*)base;                 base += K_ * N_ * 4;
    float* Gm2pm = (float*)base;                 base += N_ * 4;
    float* Gmu   = (float*)base;                 base += N_ * 4;
    float* Gb2pb = (float*)base;                 base += N_ * 4;
    float* Gbw   = (float*)base;                 base += N_ * 4;
    float* avec  = (float*)base;                 base += K_ * N_ * 4;
    float* bvec  = (float*)base;                 base += K_ * N_ * 4;
    float* rs    = (float*)base;                 base += K_ * N_ * 4;

    const dim3 blk(256);
    const dim3 g8(8, 8, 8);      // (z, m-tile, n-tile): z -> XCD
    const dim3 gsk(8, 8, 4);     // (n-tile, m-tile, k-slice): n -> XCD

    // fused setup: sigmoid cast + row moments; Gm cast + row moments
    prep_k<1><<<dim3(256, K_), blk, 0, stream>>>(atoms, Gkt, Gk2ps, Gku);
    prep_k<0><<<dim3(256, 1), blk, 0, stream>>>(Gm, Gmt, Gm2pm, Gmu);

    for (int it = 0; it < GWBL; ++it) {
        // iteration 0: barycenter == Gm (no copy needed)
        const bfu*   GbtU = it ? Gbt : Gmt;
        const float* d2U  = it ? Gb2pb : Gm2pm;
        const float* wU   = it ? Gbw : Gmu;

        // OT step 0: rank-1 analytic prox + fused first-b
        prox1_k<<<512 * K_, blk, 0, stream>>>(Tt, Gk2ps, Gku, d2U, wU,
                                              probs, pm, bvec, N_, K_);
        sink_tail<K_, 0>(Tt, probs, N_, pm, avec, bvec, rs, stream);
        for (int ot = 1; ot < OTL; ++ot) {
            // M[i][n] = sum_k Gk[i][k]*Tt[n][k]  (= Gs @ T); zero rs for prox
            bgemm_k<0><<<g8, blk, 0, stream>>>(Gkt, Tt, M, NN, NN, NN,
                nullptr, nullptr, nullptr, rs);
            // prox in place + row-sum atomics -> rs
            bgemm_k<2><<<g8, blk, 0, stream>>>(GbtU, M, Tt, 0, NN, NN,
                Gk2ps, d2U, nullptr, rs);
            sink_tail<K_, 1>(Tt, probs, N_, pm, avec, bvec, rs, stream);
        }
        // GTt[j][i'] = sum_k Tt[j][k]*Gk[i'][k]   (= (Gk @ T)^T)
        bgemm_k<0><<<g8, blk, 0, stream>>>(Tt, Gkt, M, NN, NN, NN,
            nullptr, nullptr, nullptr, nullptr);
        // part[z][i][j] = w_z * sum_n Tt[z][i][n]*GTt[z][j][n]
        bgemm_k<1><<<g8, blk, 0, stream>>>(Tt, M, part, NN, NN, NN,
            nullptr, nullptr, wts, nullptr);
        // Gb row combine + moments (+ fp32 G_bary to out on last iter)
        reduce8_k<<<512, blk, 0, stream>>>(part, Gbt, Gb2pb, Gbw,
                                           (it == GWBL - 1) ? out + 1 : nullptr);
    }

    // ---- final fgwd(Gm, pm, Gb, pm) ----
    prox1_k<<<512, blk, 0, stream>>>(Tt, Gm2pm, Gmu, Gb2pb, Gbw, pm, pm, bvec, 0, 1);
    sink_tail<1, 0>(Tt, pm, 0, pm, avec, bvec, rs, stream);
    for (int ot = 1; ot < OTL; ++ot) {
        gemm_splitk_k<<<gsk, blk, 0, stream>>>(Gmt, Tt, part);
        comb_k<0><<<512, blk, 0, stream>>>(part, M, nullptr, nullptr,
                                           nullptr, nullptr, nullptr);
        gemm_splitk_k<<<gsk, blk, 0, stream>>>(Gbt, M, part);
        comb_k<2><<<512, blk, 0, stream>>>(part, Tt, Gm2pm, Gb2pb,
                                           nullptr, pm, bvec);
        sink_tail<1, 0>(Tt, pm, 0, pm, avec, bvec, rs, stream);
    }
    // d = sum_ij (Gm2pm[i] + Gb2pb[j] - 2*(Gm T Gb^T)[i][j]) * T[i][j]
    gemm_splitk_k<<<gsk, blk, 0, stream>>>(Gmt, Tt, part);
    comb_k<0><<<512, blk, 0, stream>>>(part, M, nullptr, nullptr,
                                       out /* zero d */, nullptr, nullptr);
    gemm_splitk_k<<<gsk, blk, 0, stream>>>(Gbt, M, part);
    comb_k<3><<<512, blk, 0, stream>>>(part, Tt, Gm2pm, Gb2pb, out, nullptr, nullptr);
}